// Round 2
// baseline (15813.603 us; speedup 1.0000x reference)
//
#include <hip/hip_runtime.h>
#include <math.h>

#define BATCH 16
#define H1 224
#define C1 64
#define HP 28
#define P2 784            // 28*28
#define C2 192
#define NQ ((size_t)BATCH*C2*P2)       // 2408448
#define CHW ((size_t)C1*H1*H1)         // 3211264 floats per image

// ---------------- conv 7x7 pad3 (3->64) + BN + ReLU ----------------
// grid (14,14, ck*16), block (16,16). 4 output channels per thread.
__global__ __launch_bounds__(256) void conv7_bnrelu(
    const float* __restrict__ x, const float* __restrict__ w,
    const float* __restrict__ bn, float* __restrict__ out)
{
  __shared__ __align__(16) float wls[147 * 4];  // [tap][oo]
  int tid = threadIdx.y * 16 + threadIdx.x;
  int b = blockIdx.z >> 4, og = blockIdx.z & 15;
  int o0 = og * 4;
  for (int idx = tid; idx < 588; idx += 256) {
    int tap = idx >> 2, oo = idx & 3;
    wls[tap * 4 + oo] = w[(o0 + oo) * 147 + tap];
  }
  __syncthreads();
  int ox = blockIdx.x * 16 + threadIdx.x;
  int oy = blockIdx.y * 16 + threadIdx.y;
  float a0 = 0.f, a1 = 0.f, a2 = 0.f, a3 = 0.f;
  for (int i = 0; i < 3; i++) {
    const float* xp = x + (size_t)((b * 3 + i) * H1) * H1;
    #pragma unroll
    for (int dy = 0; dy < 7; dy++) {
      int yy = oy + dy - 3;
      bool yok = (yy >= 0 && yy < H1);
      #pragma unroll
      for (int dx = 0; dx < 7; dx++) {
        int xx = ox + dx - 3;
        float xv = (yok && xx >= 0 && xx < H1) ? xp[yy * H1 + xx] : 0.0f;
        const float4 wv = *(const float4*)&wls[(i * 49 + dy * 7 + dx) * 4];
        a0 = fmaf(wv.x, xv, a0);
        a1 = fmaf(wv.y, xv, a1);
        a2 = fmaf(wv.z, xv, a2);
        a3 = fmaf(wv.w, xv, a3);
      }
    }
  }
  const float inv = 1.0f / sqrtf(1.0f + 1e-5f);
  float accs[4] = {a0, a1, a2, a3};
  #pragma unroll
  for (int oo = 0; oo < 4; oo++) {
    int o = o0 + oo;
    float sc = bn[o] * inv, be = bn[64 + o];
    out[((size_t)(b * C1 + o) * H1 + oy) * H1 + ox] = fmaxf(accs[oo] * sc + be, 0.0f);
  }
}

// ---------------- conv 3x3 pad1 (64->64) + BN + ReLU ----------------
// grid (7,7, ck*4), block (16,16). 32x32 spatial tile, 16 o-ch per block,
// 2x2 outputs per thread.
__global__ __launch_bounds__(256) void conv3_bnrelu(
    const float* __restrict__ x, const float* __restrict__ w,
    const float* __restrict__ bn, float* __restrict__ out)
{
  __shared__ __align__(16) float xs[34][36];
  __shared__ __align__(16) float ws[16][12];
  int tx = threadIdx.x, ty = threadIdx.y;
  int tid = ty * 16 + tx;
  int b = blockIdx.z >> 2;
  int o0 = (blockIdx.z & 3) * 16;
  int x0 = blockIdx.x * 32, y0 = blockIdx.y * 32;
  float acc[16][2][2];
  #pragma unroll
  for (int oo = 0; oo < 16; oo++)
    #pragma unroll
    for (int r = 0; r < 2; r++)
      #pragma unroll
      for (int c = 0; c < 2; c++) acc[oo][r][c] = 0.0f;

  for (int i = 0; i < 64; i++) {
    __syncthreads();
    const float* xp = x + (size_t)((b * C1 + i) * H1) * H1;
    for (int idx = tid; idx < 34 * 34; idx += 256) {
      int r = idx / 34, c = idx - r * 34;
      int gy = y0 - 1 + r, gx = x0 - 1 + c;
      xs[r][c] = (gy >= 0 && gy < H1 && gx >= 0 && gx < H1) ? xp[gy * H1 + gx] : 0.0f;
    }
    if (tid < 144) {
      int oo = tid / 9, tap = tid - oo * 9;
      ws[oo][tap] = w[((size_t)(o0 + oo) * 64 + i) * 9 + tap];
    }
    __syncthreads();
    float xv[4][4];
    #pragma unroll
    for (int r = 0; r < 4; r++)
      #pragma unroll
      for (int c = 0; c < 4; c++) xv[r][c] = xs[2 * ty + r][2 * tx + c];
    #pragma unroll
    for (int oo = 0; oo < 16; oo++) {
      float w0 = ws[oo][0], w1 = ws[oo][1], w2 = ws[oo][2];
      float w3 = ws[oo][3], w4 = ws[oo][4], w5 = ws[oo][5];
      float w6 = ws[oo][6], w7 = ws[oo][7], w8 = ws[oo][8];
      #pragma unroll
      for (int r = 0; r < 2; r++)
        #pragma unroll
        for (int c = 0; c < 2; c++) {
          float s = acc[oo][r][c];
          s = fmaf(w0, xv[r][c], s);
          s = fmaf(w1, xv[r][c + 1], s);
          s = fmaf(w2, xv[r][c + 2], s);
          s = fmaf(w3, xv[r + 1][c], s);
          s = fmaf(w4, xv[r + 1][c + 1], s);
          s = fmaf(w5, xv[r + 1][c + 2], s);
          s = fmaf(w6, xv[r + 2][c], s);
          s = fmaf(w7, xv[r + 2][c + 1], s);
          s = fmaf(w8, xv[r + 2][c + 2], s);
          acc[oo][r][c] = s;
        }
    }
  }
  const float inv = 1.0f / sqrtf(1.0f + 1e-5f);
  #pragma unroll
  for (int oo = 0; oo < 16; oo++) {
    int o = o0 + oo;
    float sc = bn[o] * inv, be = bn[64 + o];
    #pragma unroll
    for (int r = 0; r < 2; r++)
      #pragma unroll
      for (int c = 0; c < 2; c++) {
        int oy = y0 + 2 * ty + r, ox = x0 + 2 * tx + c;
        out[((size_t)(b * C1 + o) * H1 + oy) * H1 + ox] =
            fmaxf(acc[oo][r][c] * sc + be, 0.0f);
      }
  }
}

// ---------------- proj conv 8x8 stride 8 (64->192) + bias ----------------
// grid (28, ck), block 224 = 32 og * 7 px-quads. 6 o-ch x 4 px per thread.
__global__ __launch_bounds__(224) void proj8(
    const float* __restrict__ x, const float* __restrict__ w,
    const float* __restrict__ bias, float* __restrict__ out)
{
  int tid = threadIdx.x;
  int sub = tid % 7, og = tid / 7;  // og 0..31
  int px0 = sub * 4;
  int py = blockIdx.x, b = blockIdx.y;
  float acc[6][4];
  #pragma unroll
  for (int j = 0; j < 6; j++) {
    float bv = bias[og + 32 * j];
    #pragma unroll
    for (int p = 0; p < 4; p++) acc[j][p] = bv;
  }
  for (int i = 0; i < 64; i++) {
    const float* xp = x + (size_t)((b * C1 + i) * H1 + 8 * py) * H1;
    const float* wp = w + (size_t)i * 64;
    #pragma unroll
    for (int dy = 0; dy < 8; dy++) {
      float4 xv[8];
      const float4* xr = (const float4*)(xp + dy * H1 + px0 * 8);
      #pragma unroll
      for (int q = 0; q < 8; q++) xv[q] = xr[q];
      #pragma unroll
      for (int j = 0; j < 6; j++) {
        int o = og + 32 * j;
        const float4* wr = (const float4*)(wp + (size_t)o * 4096 + dy * 8);
        float4 w0 = wr[0], w1 = wr[1];
        #pragma unroll
        for (int p = 0; p < 4; p++) {
          float4 a = xv[2 * p], bb = xv[2 * p + 1];
          float s = acc[j][p];
          s = fmaf(w0.x, a.x, s);
          s = fmaf(w0.y, a.y, s);
          s = fmaf(w0.z, a.z, s);
          s = fmaf(w0.w, a.w, s);
          s = fmaf(w1.x, bb.x, s);
          s = fmaf(w1.y, bb.y, s);
          s = fmaf(w1.z, bb.z, s);
          s = fmaf(w1.w, bb.w, s);
          acc[j][p] = s;
        }
      }
    }
  }
  #pragma unroll
  for (int j = 0; j < 6; j++) {
    int o = og + 32 * j;
    #pragma unroll
    for (int p = 0; p < 4; p++)
      out[((size_t)(b * C2 + o) * HP + py) * HP + px0 + p] = acc[j][p];
  }
}

// ---------------- fused q/k/v 1x1 projections ----------------
// grid (4, 144, B), block 256. by/48 selects q|k|v; 4 o per thread.
__global__ __launch_bounds__(256) void qkv192(
    const float* __restrict__ xq, const float* __restrict__ xkv,
    const float* __restrict__ w, const float* __restrict__ bias,
    float* __restrict__ out)
{
  int p = blockIdx.x * 256 + threadIdx.x;
  if (p >= P2) return;
  int by = blockIdx.y;
  int which = by / 48, o0 = (by % 48) * 4;
  int b = blockIdx.z;
  const float* xp = (which == 0 ? xq : xkv) + (size_t)b * C2 * P2 + p;
  const float* wp = w + (size_t)which * C2 * C2 + (size_t)o0 * C2;
  float a0 = bias[which * C2 + o0 + 0];
  float a1 = bias[which * C2 + o0 + 1];
  float a2 = bias[which * C2 + o0 + 2];
  float a3 = bias[which * C2 + o0 + 3];
  #pragma unroll 8
  for (int c = 0; c < C2; c++) {
    float xv = xp[(size_t)c * P2];
    a0 = fmaf(wp[c], xv, a0);
    a1 = fmaf(wp[C2 + c], xv, a1);
    a2 = fmaf(wp[2 * C2 + c], xv, a2);
    a3 = fmaf(wp[3 * C2 + c], xv, a3);
  }
  float* op = out + (size_t)which * NQ + ((size_t)b * C2 + o0) * P2 + p;
  op[0] = a0; op[P2] = a1; op[2 * P2] = a2; op[3 * P2] = a3;
}

// ---------------- per-(b,c) attention core ----------------
// grid (192, B), block 256.
__global__ __launch_bounds__(256) void attn_core(
    const float* __restrict__ qkv, float* __restrict__ out)
{
  __shared__ __align__(16) float qs[P2], ks[P2], vs[P2];
  __shared__ __align__(16) float As[28][29];
  int c = blockIdx.x, b = blockIdx.y;
  int tid = threadIdx.x;
  size_t base = ((size_t)b * C2 + c) * P2;
  const float* Q = qkv + base;
  const float* K = qkv + NQ + base;
  const float* V = qkv + 2 * NQ + base;
  for (int idx = tid; idx < P2; idx += 256) {
    qs[idx] = Q[idx]; ks[idx] = K[idx]; vs[idx] = V[idx];
  }
  __syncthreads();
  const float scl = 1.0f / sqrtf(28.0f);
  for (int idx = tid; idx < P2; idx += 256) {
    int h = idx / 28, g = idx - 28 * h;
    float s = 0.f;
    #pragma unroll
    for (int ww = 0; ww < 28; ww++) s = fmaf(qs[h * 28 + ww], ks[g * 28 + ww], s);
    As[h][g] = s * scl;
  }
  __syncthreads();
  if (tid < 28) {
    float m = -1e30f;
    #pragma unroll
    for (int g = 0; g < 28; g++) m = fmaxf(m, As[tid][g]);
    float sum = 0.f;
    #pragma unroll
    for (int g = 0; g < 28; g++) {
      float e = expf(As[tid][g] - m);
      As[tid][g] = e;
      sum += e;
    }
    float r = 1.0f / sum;
    #pragma unroll
    for (int g = 0; g < 28; g++) As[tid][g] *= r;
  }
  __syncthreads();
  for (int idx = tid; idx < P2; idx += 256) {
    int h = idx / 28, ww = idx - 28 * h;
    float s = 0.f;
    #pragma unroll
    for (int g = 0; g < 28; g++) s = fmaf(As[h][g], vs[g * 28 + ww], s);
    out[base + idx] = s;
  }
}

// ---------------- 1x1 conv 192->192 + bias (attention o-proj) ----------------
__global__ __launch_bounds__(256) void pw192(
    const float* __restrict__ x, const float* __restrict__ w,
    const float* __restrict__ bias, float* __restrict__ out)
{
  int p = blockIdx.x * 256 + threadIdx.x;
  if (p >= P2) return;
  int o0 = blockIdx.y * 4;
  int b = blockIdx.z;
  const float* xp = x + (size_t)b * C2 * P2 + p;
  const float* wp = w + (size_t)o0 * C2;
  float a0 = bias[o0 + 0], a1 = bias[o0 + 1], a2 = bias[o0 + 2], a3 = bias[o0 + 3];
  #pragma unroll 8
  for (int c = 0; c < C2; c++) {
    float xv = xp[(size_t)c * P2];
    a0 = fmaf(wp[c], xv, a0);
    a1 = fmaf(wp[C2 + c], xv, a1);
    a2 = fmaf(wp[2 * C2 + c], xv, a2);
    a3 = fmaf(wp[3 * C2 + c], xv, a3);
  }
  float* op = out + ((size_t)b * C2 + o0) * P2 + p;
  op[0] = a0; op[P2] = a1; op[2 * P2] = a2; op[3 * P2] = a3;
}

// ---------------- concat + 1x1 conv 384->192 + BN + ReLU ----------------
__global__ __launch_bounds__(256) void cov_bnrelu(
    const float* __restrict__ fo, const float* __restrict__ bo,
    const float* __restrict__ w, const float* __restrict__ g,
    const float* __restrict__ be, float* __restrict__ out)
{
  int p = blockIdx.x * 256 + threadIdx.x;
  if (p >= P2) return;
  int o0 = blockIdx.y * 4;
  int b = blockIdx.z;
  float a[4] = {0.f, 0.f, 0.f, 0.f};
  const float* wp = w + (size_t)o0 * 384;
  const float* xp = fo + (size_t)b * C2 * P2 + p;
  #pragma unroll 8
  for (int c = 0; c < C2; c++) {
    float xv = xp[(size_t)c * P2];
    #pragma unroll
    for (int oo = 0; oo < 4; oo++) a[oo] = fmaf(wp[oo * 384 + c], xv, a[oo]);
  }
  xp = bo + (size_t)b * C2 * P2 + p;
  #pragma unroll 8
  for (int c = 0; c < C2; c++) {
    float xv = xp[(size_t)c * P2];
    #pragma unroll
    for (int oo = 0; oo < 4; oo++) a[oo] = fmaf(wp[oo * 384 + 192 + c], xv, a[oo]);
  }
  const float inv = 1.0f / sqrtf(1.0f + 1e-5f);
  #pragma unroll
  for (int oo = 0; oo < 4; oo++) {
    int o = o0 + oo;
    out[((size_t)b * C2 + o) * P2 + p] = fmaxf(a[oo] * (g[o] * inv) + be[o], 0.0f);
  }
}

extern "C" void kernel_launch(void* const* d_in, const int* in_sizes, int n_in,
                              void* d_out, int out_size, void* d_ws, size_t ws_size,
                              hipStream_t stream) {
  (void)in_sizes; (void)n_in; (void)out_size;
  const float* face = (const float*)d_in[0];
  const float* body = (const float*)d_in[1];
  const float* f_w1 = (const float*)d_in[2];
  const float* f_w23 = (const float*)d_in[3];
  const float* f_bn = (const float*)d_in[4];
  const float* f_pw = (const float*)d_in[5];
  const float* f_pb = (const float*)d_in[6];
  const float* b_w1 = (const float*)d_in[7];
  const float* b_w23 = (const float*)d_in[8];
  const float* b_bn = (const float*)d_in[9];
  const float* b_pw = (const float*)d_in[10];
  const float* b_pb = (const float*)d_in[11];
  const float* a1_qkv_w = (const float*)d_in[12];
  const float* a1_qkv_b = (const float*)d_in[13];
  const float* a1_o_w = (const float*)d_in[14];
  const float* a1_o_b = (const float*)d_in[15];
  const float* a2_qkv_w = (const float*)d_in[16];
  const float* a2_qkv_b = (const float*)d_in[17];
  const float* a2_o_w = (const float*)d_in[18];
  const float* a2_o_b = (const float*)d_in[19];
  const float* cov_w = (const float*)d_in[20];
  const float* cov_g = (const float*)d_in[21];
  const float* cov_b = (const float*)d_in[22];
  float* out = (float*)d_out;

  // ---- workspace budget: pick stem batch-chunk so we never exceed ws_size ----
  // layout: [embf NQ][embb NQ][big = max(2*ck*CHW, 6*NQ)]
  size_t availF = ws_size / sizeof(float);
  int ck = 4;                                   // 122 MB total
  {
    size_t need4 = 2 * NQ + 2 * (size_t)4 * CHW;
    if (need4 > availF) ck = 2;                 // 77 MB total (floor)
  }

  float* ws = (float*)d_ws;
  float* embf = ws;
  float* embb = ws + NQ;
  float* big  = ws + 2 * NQ;
  float* sb0 = big;
  float* sb1 = big + (size_t)ck * CHW;
  // attention scratch aliased into `big` after stems complete:
  float* qkv = big;
  float* att = big + 3 * NQ;
  float* fo  = big + 4 * NQ;
  float* bo  = big + 5 * NQ;

  dim3 blk2(16, 16);

  // --- face patch embed (chunked over batch) ---
  for (int c0 = 0; c0 < BATCH; c0 += ck) {
    const float* xin = face + (size_t)c0 * 3 * H1 * H1;
    conv7_bnrelu<<<dim3(14, 14, ck * 16), blk2, 0, stream>>>(xin, f_w1, f_bn, sb0);
    conv3_bnrelu<<<dim3(7, 7, ck * 4), blk2, 0, stream>>>(sb0, f_w23, f_bn + 128, sb1);
    conv3_bnrelu<<<dim3(7, 7, ck * 4), blk2, 0, stream>>>(sb1, f_w23 + 36864, f_bn + 256, sb0);
    proj8<<<dim3(HP, ck), 224, 0, stream>>>(sb0, f_pw, f_pb, embf + (size_t)c0 * C2 * P2);
  }

  // --- body patch embed (chunked over batch) ---
  for (int c0 = 0; c0 < BATCH; c0 += ck) {
    const float* xin = body + (size_t)c0 * 3 * H1 * H1;
    conv7_bnrelu<<<dim3(14, 14, ck * 16), blk2, 0, stream>>>(xin, b_w1, b_bn, sb0);
    conv3_bnrelu<<<dim3(7, 7, ck * 4), blk2, 0, stream>>>(sb0, b_w23, b_bn + 128, sb1);
    conv3_bnrelu<<<dim3(7, 7, ck * 4), blk2, 0, stream>>>(sb1, b_w23 + 36864, b_bn + 256, sb0);
    proj8<<<dim3(HP, ck), 224, 0, stream>>>(sb0, b_pw, b_pb, embb + (size_t)c0 * C2 * P2);
  }

  // --- attention 1: q from face-embed, k/v from body-embed ---
  qkv192<<<dim3(4, 144, BATCH), 256, 0, stream>>>(embf, embb, a1_qkv_w, a1_qkv_b, qkv);
  attn_core<<<dim3(C2, BATCH), 256, 0, stream>>>(qkv, att);
  pw192<<<dim3(4, 48, BATCH), 256, 0, stream>>>(att, a1_o_w, a1_o_b, fo);

  // --- attention 2: q from body-embed, k/v from face-embed ---
  qkv192<<<dim3(4, 144, BATCH), 256, 0, stream>>>(embb, embf, a2_qkv_w, a2_qkv_b, qkv);
  attn_core<<<dim3(C2, BATCH), 256, 0, stream>>>(qkv, att);
  pw192<<<dim3(4, 48, BATCH), 256, 0, stream>>>(att, a2_o_w, a2_o_b, bo);

  // --- concat + cov 1x1 + BN + ReLU ---
  cov_bnrelu<<<dim3(4, 48, BATCH), 256, 0, stream>>>(fo, bo, cov_w, cov_g, cov_b, out);
}

// Round 3
// 10515.665 us; speedup vs baseline: 1.5038x; 1.5038x over previous
//
#include <hip/hip_runtime.h>
#include <math.h>

#define BATCH 16
#define H1 224
#define C1 64
#define HP 28
#define P2 784            // 28*28
#define C2 192
#define NQ ((size_t)BATCH*C2*P2)       // 2408448
#define CHW ((size_t)C1*H1*H1)         // 3211264 floats per image

// ---------------- conv 7x7 pad3 (3->64) + BN + ReLU ----------------
// grid (14,14, ck*16), block (16,16). 4 output channels per thread.
__global__ __launch_bounds__(256) void conv7_bnrelu(
    const float* __restrict__ x, const float* __restrict__ w,
    const float* __restrict__ bn, float* __restrict__ out)
{
  __shared__ __align__(16) float wls[147 * 4];  // [tap][oo]
  int tid = threadIdx.y * 16 + threadIdx.x;
  int b = blockIdx.z >> 4, og = blockIdx.z & 15;
  int o0 = og * 4;
  for (int idx = tid; idx < 588; idx += 256) {
    int tap = idx >> 2, oo = idx & 3;
    wls[tap * 4 + oo] = w[(o0 + oo) * 147 + tap];
  }
  __syncthreads();
  int ox = blockIdx.x * 16 + threadIdx.x;
  int oy = blockIdx.y * 16 + threadIdx.y;
  float a0 = 0.f, a1 = 0.f, a2 = 0.f, a3 = 0.f;
  for (int i = 0; i < 3; i++) {
    const float* xp = x + (size_t)((b * 3 + i) * H1) * H1;
    #pragma unroll
    for (int dy = 0; dy < 7; dy++) {
      int yy = oy + dy - 3;
      bool yok = (yy >= 0 && yy < H1);
      #pragma unroll
      for (int dx = 0; dx < 7; dx++) {
        int xx = ox + dx - 3;
        float xv = (yok && xx >= 0 && xx < H1) ? xp[yy * H1 + xx] : 0.0f;
        const float4 wv = *(const float4*)&wls[(i * 49 + dy * 7 + dx) * 4];
        a0 = fmaf(wv.x, xv, a0);
        a1 = fmaf(wv.y, xv, a1);
        a2 = fmaf(wv.z, xv, a2);
        a3 = fmaf(wv.w, xv, a3);
      }
    }
  }
  const float inv = 1.0f / sqrtf(1.0f + 1e-5f);
  float accs[4] = {a0, a1, a2, a3};
  #pragma unroll
  for (int oo = 0; oo < 4; oo++) {
    int o = o0 + oo;
    float sc = bn[o] * inv, be = bn[64 + o];
    out[((size_t)(b * C1 + o) * H1 + oy) * H1 + ox] = fmaxf(accs[oo] * sc + be, 0.0f);
  }
}

// ---------------- conv 3x3 pad1 (64->64) + BN + ReLU ----------------
// grid (7,7, ck*4), block (16,16). 32x32 spatial tile, 16 o-ch per block,
// 2x2 outputs per thread.
__global__ __launch_bounds__(256) void conv3_bnrelu(
    const float* __restrict__ x, const float* __restrict__ w,
    const float* __restrict__ bn, float* __restrict__ out)
{
  __shared__ __align__(16) float xs[34][36];
  __shared__ __align__(16) float ws[16][12];
  int tx = threadIdx.x, ty = threadIdx.y;
  int tid = ty * 16 + tx;
  int b = blockIdx.z >> 2;
  int o0 = (blockIdx.z & 3) * 16;
  int x0 = blockIdx.x * 32, y0 = blockIdx.y * 32;
  float acc[16][2][2];
  #pragma unroll
  for (int oo = 0; oo < 16; oo++)
    #pragma unroll
    for (int r = 0; r < 2; r++)
      #pragma unroll
      for (int c = 0; c < 2; c++) acc[oo][r][c] = 0.0f;

  for (int i = 0; i < 64; i++) {
    __syncthreads();
    const float* xp = x + (size_t)((b * C1 + i) * H1) * H1;
    for (int idx = tid; idx < 34 * 34; idx += 256) {
      int r = idx / 34, c = idx - r * 34;
      int gy = y0 - 1 + r, gx = x0 - 1 + c;
      xs[r][c] = (gy >= 0 && gy < H1 && gx >= 0 && gx < H1) ? xp[gy * H1 + gx] : 0.0f;
    }
    if (tid < 144) {
      int oo = tid / 9, tap = tid - oo * 9;
      ws[oo][tap] = w[((size_t)(o0 + oo) * 64 + i) * 9 + tap];
    }
    __syncthreads();
    float xv[4][4];
    #pragma unroll
    for (int r = 0; r < 4; r++)
      #pragma unroll
      for (int c = 0; c < 4; c++) xv[r][c] = xs[2 * ty + r][2 * tx + c];
    #pragma unroll
    for (int oo = 0; oo < 16; oo++) {
      float w0 = ws[oo][0], w1 = ws[oo][1], w2 = ws[oo][2];
      float w3 = ws[oo][3], w4 = ws[oo][4], w5 = ws[oo][5];
      float w6 = ws[oo][6], w7 = ws[oo][7], w8 = ws[oo][8];
      #pragma unroll
      for (int r = 0; r < 2; r++)
        #pragma unroll
        for (int c = 0; c < 2; c++) {
          float s = acc[oo][r][c];
          s = fmaf(w0, xv[r][c], s);
          s = fmaf(w1, xv[r][c + 1], s);
          s = fmaf(w2, xv[r][c + 2], s);
          s = fmaf(w3, xv[r + 1][c], s);
          s = fmaf(w4, xv[r + 1][c + 1], s);
          s = fmaf(w5, xv[r + 1][c + 2], s);
          s = fmaf(w6, xv[r + 2][c], s);
          s = fmaf(w7, xv[r + 2][c + 1], s);
          s = fmaf(w8, xv[r + 2][c + 2], s);
          acc[oo][r][c] = s;
        }
    }
  }
  const float inv = 1.0f / sqrtf(1.0f + 1e-5f);
  #pragma unroll
  for (int oo = 0; oo < 16; oo++) {
    int o = o0 + oo;
    float sc = bn[o] * inv, be = bn[64 + o];
    #pragma unroll
    for (int r = 0; r < 2; r++)
      #pragma unroll
      for (int c = 0; c < 2; c++) {
        int oy = y0 + 2 * ty + r, ox = x0 + 2 * tx + c;
        out[((size_t)(b * C1 + o) * H1 + oy) * H1 + ox] =
            fmaxf(acc[oo][r][c] * sc + be, 0.0f);
      }
  }
}

// ---------------- proj conv 8x8 stride 8 (64->192) + bias, as tiled GEMM ----
// out[b,o,p] = bias[o] + sum_k w[o,k] * patch[b,p,k],  k = i*64 + dy*8 + dx
// grid (13 ptiles, 3 otiles, ck), block (16,16).
// Tile: 64 patches x 64 outs, BK=64 (one input channel). 4x4 reg tile,
// strided p/o mapping (p = ty+16*pi, o = tx+16*oi) for bank spread.
#define PJS 68  // LDS row stride (floats): 17 granules, odd -> banks spread
__global__ __launch_bounds__(256) void proj8_gemm(
    const float* __restrict__ x, const float* __restrict__ w,
    const float* __restrict__ bias, float* __restrict__ out)
{
  __shared__ __align__(16) float As[64 * PJS];
  __shared__ __align__(16) float Bs[64 * PJS];
  int tx = threadIdx.x, ty = threadIdx.y;
  int tid = ty * 16 + tx;
  int p0 = blockIdx.x * 64;
  int o0 = blockIdx.y * 64;
  int b = blockIdx.z;
  float acc[4][4];
  #pragma unroll
  for (int pi = 0; pi < 4; pi++)
    #pragma unroll
    for (int oi = 0; oi < 4; oi++) acc[pi][oi] = 0.0f;

  for (int i = 0; i < 64; i++) {
    __syncthreads();
    // --- stage B: w[o0+oo][i*64 + tap], 64 rows x 64 taps, 1024 float4 ---
    #pragma unroll
    for (int q = 0; q < 4; q++) {
      int f = q * 256 + tid;            // f4 index
      int oo = f >> 4, t4 = f & 15;
      const float4 wv = *(const float4*)(w + ((size_t)(o0 + oo) * 4096) + i * 64 + t4 * 4);
      *(float4*)&Bs[oo * PJS + t4 * 4] = wv;
    }
    // --- stage A: patch p=p0+pp, tap=dy*8+dx -> x[(b,i), 8*py+dy, 8*px+dx] ---
    #pragma unroll
    for (int q = 0; q < 4; q++) {
      int f = q * 256 + tid;            // f4 index in [0,1024)
      int pp = f >> 4, dy = (f >> 1) & 7, half = f & 1;
      int p = p0 + pp;
      float4 xv = make_float4(0.f, 0.f, 0.f, 0.f);
      if (p < P2) {
        int py = p / 28, px = p - 28 * py;
        xv = *(const float4*)(x + ((size_t)(b * C1 + i) * H1 + 8 * py + dy) * H1 + 8 * px + half * 4);
      }
      *(float4*)&As[pp * PJS + dy * 8 + half * 4] = xv;
    }
    __syncthreads();
    // --- compute: 16 steps of 4 taps ---
    #pragma unroll 4
    for (int t4 = 0; t4 < 16; t4++) {
      float4 av[4], bv[4];
      #pragma unroll
      for (int pi = 0; pi < 4; pi++)
        av[pi] = *(const float4*)&As[(ty + 16 * pi) * PJS + t4 * 4];
      #pragma unroll
      for (int oi = 0; oi < 4; oi++)
        bv[oi] = *(const float4*)&Bs[(tx + 16 * oi) * PJS + t4 * 4];
      #pragma unroll
      for (int pi = 0; pi < 4; pi++)
        #pragma unroll
        for (int oi = 0; oi < 4; oi++) {
          float s = acc[pi][oi];
          s = fmaf(av[pi].x, bv[oi].x, s);
          s = fmaf(av[pi].y, bv[oi].y, s);
          s = fmaf(av[pi].z, bv[oi].z, s);
          s = fmaf(av[pi].w, bv[oi].w, s);
          acc[pi][oi] = s;
        }
    }
  }
  #pragma unroll
  for (int pi = 0; pi < 4; pi++) {
    int p = p0 + ty + 16 * pi;
    if (p >= P2) continue;
    #pragma unroll
    for (int oi = 0; oi < 4; oi++) {
      int o = o0 + tx + 16 * oi;
      out[((size_t)(b * C2 + o)) * P2 + p] = acc[pi][oi] + bias[o];
    }
  }
}

// ---------------- fused q/k/v 1x1 projections ----------------
// grid (4, 144, B), block 256. by/48 selects q|k|v; 4 o per thread.
__global__ __launch_bounds__(256) void qkv192(
    const float* __restrict__ xq, const float* __restrict__ xkv,
    const float* __restrict__ w, const float* __restrict__ bias,
    float* __restrict__ out)
{
  int p = blockIdx.x * 256 + threadIdx.x;
  if (p >= P2) return;
  int by = blockIdx.y;
  int which = by / 48, o0 = (by % 48) * 4;
  int b = blockIdx.z;
  const float* xp = (which == 0 ? xq : xkv) + (size_t)b * C2 * P2 + p;
  const float* wp = w + (size_t)which * C2 * C2 + (size_t)o0 * C2;
  float a0 = bias[which * C2 + o0 + 0];
  float a1 = bias[which * C2 + o0 + 1];
  float a2 = bias[which * C2 + o0 + 2];
  float a3 = bias[which * C2 + o0 + 3];
  #pragma unroll 8
  for (int c = 0; c < C2; c++) {
    float xv = xp[(size_t)c * P2];
    a0 = fmaf(wp[c], xv, a0);
    a1 = fmaf(wp[C2 + c], xv, a1);
    a2 = fmaf(wp[2 * C2 + c], xv, a2);
    a3 = fmaf(wp[3 * C2 + c], xv, a3);
  }
  float* op = out + (size_t)which * NQ + ((size_t)b * C2 + o0) * P2 + p;
  op[0] = a0; op[P2] = a1; op[2 * P2] = a2; op[3 * P2] = a3;
}

// ---------------- per-(b,c) attention core ----------------
// grid (192, B), block 256.
__global__ __launch_bounds__(256) void attn_core(
    const float* __restrict__ qkv, float* __restrict__ out)
{
  __shared__ __align__(16) float qs[P2], ks[P2], vs[P2];
  __shared__ __align__(16) float As[28][29];
  int c = blockIdx.x, b = blockIdx.y;
  int tid = threadIdx.x;
  size_t base = ((size_t)b * C2 + c) * P2;
  const float* Q = qkv + base;
  const float* K = qkv + NQ + base;
  const float* V = qkv + 2 * NQ + base;
  for (int idx = tid; idx < P2; idx += 256) {
    qs[idx] = Q[idx]; ks[idx] = K[idx]; vs[idx] = V[idx];
  }
  __syncthreads();
  const float scl = 1.0f / sqrtf(28.0f);
  for (int idx = tid; idx < P2; idx += 256) {
    int h = idx / 28, g = idx - 28 * h;
    float s = 0.f;
    #pragma unroll
    for (int ww = 0; ww < 28; ww++) s = fmaf(qs[h * 28 + ww], ks[g * 28 + ww], s);
    As[h][g] = s * scl;
  }
  __syncthreads();
  if (tid < 28) {
    float m = -1e30f;
    #pragma unroll
    for (int g = 0; g < 28; g++) m = fmaxf(m, As[tid][g]);
    float sum = 0.f;
    #pragma unroll
    for (int g = 0; g < 28; g++) {
      float e = expf(As[tid][g] - m);
      As[tid][g] = e;
      sum += e;
    }
    float r = 1.0f / sum;
    #pragma unroll
    for (int g = 0; g < 28; g++) As[tid][g] *= r;
  }
  __syncthreads();
  for (int idx = tid; idx < P2; idx += 256) {
    int h = idx / 28, ww = idx - 28 * h;
    float s = 0.f;
    #pragma unroll
    for (int g = 0; g < 28; g++) s = fmaf(As[h][g], vs[g * 28 + ww], s);
    out[base + idx] = s;
  }
}

// ---------------- 1x1 conv 192->192 + bias (attention o-proj) ----------------
__global__ __launch_bounds__(256) void pw192(
    const float* __restrict__ x, const float* __restrict__ w,
    const float* __restrict__ bias, float* __restrict__ out)
{
  int p = blockIdx.x * 256 + threadIdx.x;
  if (p >= P2) return;
  int o0 = blockIdx.y * 4;
  int b = blockIdx.z;
  const float* xp = x + (size_t)b * C2 * P2 + p;
  const float* wp = w + (size_t)o0 * C2;
  float a0 = bias[o0 + 0], a1 = bias[o0 + 1], a2 = bias[o0 + 2], a3 = bias[o0 + 3];
  #pragma unroll 8
  for (int c = 0; c < C2; c++) {
    float xv = xp[(size_t)c * P2];
    a0 = fmaf(wp[c], xv, a0);
    a1 = fmaf(wp[C2 + c], xv, a1);
    a2 = fmaf(wp[2 * C2 + c], xv, a2);
    a3 = fmaf(wp[3 * C2 + c], xv, a3);
  }
  float* op = out + ((size_t)b * C2 + o0) * P2 + p;
  op[0] = a0; op[P2] = a1; op[2 * P2] = a2; op[3 * P2] = a3;
}

// ---------------- concat + 1x1 conv 384->192 + BN + ReLU ----------------
__global__ __launch_bounds__(256) void cov_bnrelu(
    const float* __restrict__ fo, const float* __restrict__ bo,
    const float* __restrict__ w, const float* __restrict__ g,
    const float* __restrict__ be, float* __restrict__ out)
{
  int p = blockIdx.x * 256 + threadIdx.x;
  if (p >= P2) return;
  int o0 = blockIdx.y * 4;
  int b = blockIdx.z;
  float a[4] = {0.f, 0.f, 0.f, 0.f};
  const float* wp = w + (size_t)o0 * 384;
  const float* xp = fo + (size_t)b * C2 * P2 + p;
  #pragma unroll 8
  for (int c = 0; c < C2; c++) {
    float xv = xp[(size_t)c * P2];
    #pragma unroll
    for (int oo = 0; oo < 4; oo++) a[oo] = fmaf(wp[oo * 384 + c], xv, a[oo]);
  }
  xp = bo + (size_t)b * C2 * P2 + p;
  #pragma unroll 8
  for (int c = 0; c < C2; c++) {
    float xv = xp[(size_t)c * P2];
    #pragma unroll
    for (int oo = 0; oo < 4; oo++) a[oo] = fmaf(wp[oo * 384 + 192 + c], xv, a[oo]);
  }
  const float inv = 1.0f / sqrtf(1.0f + 1e-5f);
  #pragma unroll
  for (int oo = 0; oo < 4; oo++) {
    int o = o0 + oo;
    out[((size_t)b * C2 + o) * P2 + p] = fmaxf(a[oo] * (g[o] * inv) + be[o], 0.0f);
  }
}

extern "C" void kernel_launch(void* const* d_in, const int* in_sizes, int n_in,
                              void* d_out, int out_size, void* d_ws, size_t ws_size,
                              hipStream_t stream) {
  (void)in_sizes; (void)n_in; (void)out_size;
  const float* face = (const float*)d_in[0];
  const float* body = (const float*)d_in[1];
  const float* f_w1 = (const float*)d_in[2];
  const float* f_w23 = (const float*)d_in[3];
  const float* f_bn = (const float*)d_in[4];
  const float* f_pw = (const float*)d_in[5];
  const float* f_pb = (const float*)d_in[6];
  const float* b_w1 = (const float*)d_in[7];
  const float* b_w23 = (const float*)d_in[8];
  const float* b_bn = (const float*)d_in[9];
  const float* b_pw = (const float*)d_in[10];
  const float* b_pb = (const float*)d_in[11];
  const float* a1_qkv_w = (const float*)d_in[12];
  const float* a1_qkv_b = (const float*)d_in[13];
  const float* a1_o_w = (const float*)d_in[14];
  const float* a1_o_b = (const float*)d_in[15];
  const float* a2_qkv_w = (const float*)d_in[16];
  const float* a2_qkv_b = (const float*)d_in[17];
  const float* a2_o_w = (const float*)d_in[18];
  const float* a2_o_b = (const float*)d_in[19];
  const float* cov_w = (const float*)d_in[20];
  const float* cov_g = (const float*)d_in[21];
  const float* cov_b = (const float*)d_in[22];
  float* out = (float*)d_out;

  // ---- workspace budget: largest stem batch-chunk that fits ws_size ----
  // layout: [embf NQ][embb NQ][big = max(2*ck*CHW, 6*NQ)]
  size_t availF = ws_size / sizeof(float);
  int ck = 2;  // floor: 77 MB
  for (int cand = 16; cand >= 4; cand >>= 1) {
    size_t bigF = 2 * (size_t)cand * CHW;
    if (bigF < 6 * NQ) bigF = 6 * NQ;
    if (2 * NQ + bigF <= availF) { ck = cand; break; }
  }

  float* ws = (float*)d_ws;
  float* embf = ws;
  float* embb = ws + NQ;
  float* big  = ws + 2 * NQ;
  float* sb0 = big;
  float* sb1 = big + (size_t)ck * CHW;
  // attention scratch aliased into `big` after stems complete:
  float* qkv = big;
  float* att = big + 3 * NQ;
  float* fo  = big + 4 * NQ;
  float* bo  = big + 5 * NQ;

  dim3 blk2(16, 16);

  // --- face patch embed (chunked over batch) ---
  for (int c0 = 0; c0 < BATCH; c0 += ck) {
    const float* xin = face + (size_t)c0 * 3 * H1 * H1;
    conv7_bnrelu<<<dim3(14, 14, ck * 16), blk2, 0, stream>>>(xin, f_w1, f_bn, sb0);
    conv3_bnrelu<<<dim3(7, 7, ck * 4), blk2, 0, stream>>>(sb0, f_w23, f_bn + 128, sb1);
    conv3_bnrelu<<<dim3(7, 7, ck * 4), blk2, 0, stream>>>(sb1, f_w23 + 36864, f_bn + 256, sb0);
    proj8_gemm<<<dim3(13, 3, ck), blk2, 0, stream>>>(sb0, f_pw, f_pb, embf + (size_t)c0 * C2 * P2);
  }

  // --- body patch embed (chunked over batch) ---
  for (int c0 = 0; c0 < BATCH; c0 += ck) {
    const float* xin = body + (size_t)c0 * 3 * H1 * H1;
    conv7_bnrelu<<<dim3(14, 14, ck * 16), blk2, 0, stream>>>(xin, b_w1, b_bn, sb0);
    conv3_bnrelu<<<dim3(7, 7, ck * 4), blk2, 0, stream>>>(sb0, b_w23, b_bn + 128, sb1);
    conv3_bnrelu<<<dim3(7, 7, ck * 4), blk2, 0, stream>>>(sb1, b_w23 + 36864, b_bn + 256, sb0);
    proj8_gemm<<<dim3(13, 3, ck), blk2, 0, stream>>>(sb0, b_pw, b_pb, embb + (size_t)c0 * C2 * P2);
  }

  // --- attention 1: q from face-embed, k/v from body-embed ---
  qkv192<<<dim3(4, 144, BATCH), 256, 0, stream>>>(embf, embb, a1_qkv_w, a1_qkv_b, qkv);
  attn_core<<<dim3(C2, BATCH), 256, 0, stream>>>(qkv, att);
  pw192<<<dim3(4, 48, BATCH), 256, 0, stream>>>(att, a1_o_w, a1_o_b, fo);

  // --- attention 2: q from body-embed, k/v from face-embed ---
  qkv192<<<dim3(4, 144, BATCH), 256, 0, stream>>>(embb, embf, a2_qkv_w, a2_qkv_b, qkv);
  attn_core<<<dim3(C2, BATCH), 256, 0, stream>>>(qkv, att);
  pw192<<<dim3(4, 48, BATCH), 256, 0, stream>>>(att, a2_o_w, a2_o_b, bo);

  // --- concat + cov 1x1 + BN + ReLU ---
  cov_bnrelu<<<dim3(4, 48, BATCH), 256, 0, stream>>>(fo, bo, cov_w, cov_g, cov_b, out);
}

// Round 6
// 6448.846 us; speedup vs baseline: 2.4522x; 1.6306x over previous
//
#include <hip/hip_runtime.h>
#include <hip/hip_bf16.h>
#include <math.h>

#define BATCH 16
#define H1 224
#define C1 64
#define HP 28
#define P2 784            // 28*28
#define C2 192
#define NQ ((size_t)BATCH*C2*P2)       // 2408448
#define CHW ((size_t)C1*H1*H1)         // 3211264 floats per image

typedef __attribute__((ext_vector_type(8))) short short8;
typedef __attribute__((ext_vector_type(4))) float f32x4;

__device__ __forceinline__ ushort f2bf(float v) {
  __hip_bfloat16 h = __float2bfloat16(v);
  return *(ushort*)&h;
}

// ---------------- conv 7x7 pad3 (3->64) + BN + ReLU ----------------
// grid (14,14, ck*16), block (16,16). 4 output channels per thread.
__global__ __launch_bounds__(256) void conv7_bnrelu(
    const float* __restrict__ x, const float* __restrict__ w,
    const float* __restrict__ bn, float* __restrict__ out)
{
  __shared__ __align__(16) float wls[147 * 4];  // [tap][oo]
  int tid = threadIdx.y * 16 + threadIdx.x;
  int b = blockIdx.z >> 4, og = blockIdx.z & 15;
  int o0 = og * 4;
  for (int idx = tid; idx < 588; idx += 256) {
    int tap = idx >> 2, oo = idx & 3;
    wls[tap * 4 + oo] = w[(o0 + oo) * 147 + tap];
  }
  __syncthreads();
  int ox = blockIdx.x * 16 + threadIdx.x;
  int oy = blockIdx.y * 16 + threadIdx.y;
  float a0 = 0.f, a1 = 0.f, a2 = 0.f, a3 = 0.f;
  for (int i = 0; i < 3; i++) {
    const float* xp = x + (size_t)((b * 3 + i) * H1) * H1;
    #pragma unroll
    for (int dy = 0; dy < 7; dy++) {
      int yy = oy + dy - 3;
      bool yok = (yy >= 0 && yy < H1);
      #pragma unroll
      for (int dx = 0; dx < 7; dx++) {
        int xx = ox + dx - 3;
        float xv = (yok && xx >= 0 && xx < H1) ? xp[yy * H1 + xx] : 0.0f;
        const float4 wv = *(const float4*)&wls[(i * 49 + dy * 7 + dx) * 4];
        a0 = fmaf(wv.x, xv, a0);
        a1 = fmaf(wv.y, xv, a1);
        a2 = fmaf(wv.z, xv, a2);
        a3 = fmaf(wv.w, xv, a3);
      }
    }
  }
  const float inv = 1.0f / sqrtf(1.0f + 1e-5f);
  float accs[4] = {a0, a1, a2, a3};
  #pragma unroll
  for (int oo = 0; oo < 4; oo++) {
    int o = o0 + oo;
    float sc = bn[o] * inv, be = bn[64 + o];
    out[((size_t)(b * C1 + o) * H1 + oy) * H1 + ox] = fmaxf(accs[oo] * sc + be, 0.0f);
  }
}

// ---------------- conv 3x3 pad1 (64->64) + BN + ReLU, bf16 MFMA ----------------
// grid (7, 28, ck), block 256 (4 waves).
// Block tile: 64 och x (8 rows x 32 cols). Wave: 64 och x (2 rows x 32 cols),
// 4x4 fragment tile of mfma_f32_16x16x32_bf16. K = 2 ich-chunks x 9 taps.
// LDS pad 40 (80 B col stride): 16B-aligned b128, 8 accesses/bank (conflict-free).
__global__ __launch_bounds__(256) void conv3_mfma(
    const float* __restrict__ x, const float* __restrict__ w,
    const float* __restrict__ bn, float* __restrict__ out)
{
  __shared__ ushort in_lds[10][34][40];  // [row][col][ich] 27200 B
  __shared__ ushort w_lds[64][9][40];    // [och][tap][ich] 46080 B
  int tid = threadIdx.x;
  int wv = tid >> 6, lane = tid & 63;
  int l15 = lane & 15, q = lane >> 4;
  int x0 = blockIdx.x * 32, y0 = blockIdx.y * 8;
  int b = blockIdx.z;

  f32x4 acc[4][4];
  #pragma unroll
  for (int m = 0; m < 4; m++)
    #pragma unroll
    for (int n = 0; n < 4; n++) acc[m][n] = (f32x4){0.f, 0.f, 0.f, 0.f};

  for (int ic = 0; ic < 2; ic++) {
    int ich0 = ic * 32;
    __syncthreads();
    // --- stage input: 32 ich x 10 rows x 34 cols (halo, zero-pad) ---
    for (int k = tid; k < 10880; k += 256) {
      int c = k % 34;
      int t = k / 34;
      int r = t % 10;
      int i = t / 10;
      int gy = y0 - 1 + r, gx = x0 - 1 + c;
      float v = 0.0f;
      if (gy >= 0 && gy < H1 && gx >= 0 && gx < H1)
        v = x[((size_t)(b * C1 + ich0 + i) * H1 + gy) * H1 + gx];
      in_lds[r][c][i] = f2bf(v);
    }
    // --- stage weights: 64 och x 32 ich x 9 taps ---
    for (int k = tid; k < 18432; k += 256) {
      int o = k / 288;
      int rem = k - o * 288;
      int i = rem / 9;
      int tap = rem - i * 9;
      float v = w[(size_t)o * 576 + (size_t)(ich0 + i) * 9 + tap];
      w_lds[o][tap][i] = f2bf(v);
    }
    __syncthreads();
    // --- K loop: 9 taps, K=32 ich per mfma step ---
    #pragma unroll
    for (int dy = 0; dy < 3; dy++) {
      #pragma unroll
      for (int dx = 0; dx < 3; dx++) {
        int tap = dy * 3 + dx;
        short8 afr[4];
        #pragma unroll
        for (int m = 0; m < 4; m++)
          afr[m] = *(const short8*)&w_lds[m * 16 + l15][tap][q * 8];
        short8 bfr[4];
        #pragma unroll
        for (int n = 0; n < 4; n++) {
          int r = 2 * wv + (n >> 1) + dy;
          int c = (n & 1) * 16 + l15 + dx;
          bfr[n] = *(const short8*)&in_lds[r][c][q * 8];
        }
        #pragma unroll
        for (int m = 0; m < 4; m++)
          #pragma unroll
          for (int n = 0; n < 4; n++)
            acc[m][n] = __builtin_amdgcn_mfma_f32_16x16x32_bf16(
                afr[m], bfr[n], acc[m][n], 0, 0, 0);
      }
    }
  }
  // --- epilogue: BN + ReLU, f32 store (D: col=lane&15 -> px, row=q*4+j -> och) ---
  const float inv = 1.0f / sqrtf(1.0f + 1e-5f);
  #pragma unroll
  for (int m = 0; m < 4; m++) {
    #pragma unroll
    for (int n = 0; n < 4; n++) {
      int py = y0 + 2 * wv + (n >> 1);
      int px = x0 + (n & 1) * 16 + l15;
      #pragma unroll
      for (int j = 0; j < 4; j++) {
        int och = m * 16 + q * 4 + j;
        float sc = bn[och] * inv, be = bn[64 + och];
        float v = fmaxf(acc[m][n][j] * sc + be, 0.0f);
        out[((size_t)(b * C1 + och) * H1 + py) * H1 + px] = v;
      }
    }
  }
}

// ---------------- proj conv 8x8 stride 8 (64->192) + bias, as tiled GEMM ----
#define PJS 68  // LDS row stride (floats)
__global__ __launch_bounds__(256) void proj8_gemm(
    const float* __restrict__ x, const float* __restrict__ w,
    const float* __restrict__ bias, float* __restrict__ out)
{
  __shared__ __align__(16) float As[64 * PJS];
  __shared__ __align__(16) float Bs[64 * PJS];
  int tx = threadIdx.x, ty = threadIdx.y;
  int tid = ty * 16 + tx;
  int p0 = blockIdx.x * 64;
  int o0 = blockIdx.y * 64;
  int b = blockIdx.z;
  float acc[4][4];
  #pragma unroll
  for (int pi = 0; pi < 4; pi++)
    #pragma unroll
    for (int oi = 0; oi < 4; oi++) acc[pi][oi] = 0.0f;

  for (int i = 0; i < 64; i++) {
    __syncthreads();
    #pragma unroll
    for (int qq = 0; qq < 4; qq++) {
      int f = qq * 256 + tid;
      int oo = f >> 4, t4 = f & 15;
      const float4 wv = *(const float4*)(w + ((size_t)(o0 + oo) * 4096) + i * 64 + t4 * 4);
      *(float4*)&Bs[oo * PJS + t4 * 4] = wv;
    }
    #pragma unroll
    for (int qq = 0; qq < 4; qq++) {
      int f = qq * 256 + tid;
      int pp = f >> 4, dy = (f >> 1) & 7, half = f & 1;
      int p = p0 + pp;
      float4 xv = make_float4(0.f, 0.f, 0.f, 0.f);
      if (p < P2) {
        int py = p / 28, px = p - 28 * py;
        xv = *(const float4*)(x + ((size_t)(b * C1 + i) * H1 + 8 * py + dy) * H1 + 8 * px + half * 4);
      }
      *(float4*)&As[pp * PJS + dy * 8 + half * 4] = xv;
    }
    __syncthreads();
    #pragma unroll 4
    for (int t4 = 0; t4 < 16; t4++) {
      float4 av[4], bv[4];
      #pragma unroll
      for (int pi = 0; pi < 4; pi++)
        av[pi] = *(const float4*)&As[(ty + 16 * pi) * PJS + t4 * 4];
      #pragma unroll
      for (int oi = 0; oi < 4; oi++)
        bv[oi] = *(const float4*)&Bs[(tx + 16 * oi) * PJS + t4 * 4];
      #pragma unroll
      for (int pi = 0; pi < 4; pi++)
        #pragma unroll
        for (int oi = 0; oi < 4; oi++) {
          float s = acc[pi][oi];
          s = fmaf(av[pi].x, bv[oi].x, s);
          s = fmaf(av[pi].y, bv[oi].y, s);
          s = fmaf(av[pi].z, bv[oi].z, s);
          s = fmaf(av[pi].w, bv[oi].w, s);
          acc[pi][oi] = s;
        }
    }
  }
  #pragma unroll
  for (int pi = 0; pi < 4; pi++) {
    int p = p0 + ty + 16 * pi;
    if (p >= P2) continue;
    #pragma unroll
    for (int oi = 0; oi < 4; oi++) {
      int o = o0 + tx + 16 * oi;
      out[((size_t)(b * C2 + o)) * P2 + p] = acc[pi][oi] + bias[o];
    }
  }
}

// ---------------- fused q/k/v 1x1 projections ----------------
__global__ __launch_bounds__(256) void qkv192(
    const float* __restrict__ xq, const float* __restrict__ xkv,
    const float* __restrict__ w, const float* __restrict__ bias,
    float* __restrict__ out)
{
  int p = blockIdx.x * 256 + threadIdx.x;
  if (p >= P2) return;
  int by = blockIdx.y;
  int which = by / 48, o0 = (by % 48) * 4;
  int b = blockIdx.z;
  const float* xp = (which == 0 ? xq : xkv) + (size_t)b * C2 * P2 + p;
  const float* wp = w + (size_t)which * C2 * C2 + (size_t)o0 * C2;
  float a0 = bias[which * C2 + o0 + 0];
  float a1 = bias[which * C2 + o0 + 1];
  float a2 = bias[which * C2 + o0 + 2];
  float a3 = bias[which * C2 + o0 + 3];
  #pragma unroll 8
  for (int c = 0; c < C2; c++) {
    float xv = xp[(size_t)c * P2];
    a0 = fmaf(wp[c], xv, a0);
    a1 = fmaf(wp[C2 + c], xv, a1);
    a2 = fmaf(wp[2 * C2 + c], xv, a2);
    a3 = fmaf(wp[3 * C2 + c], xv, a3);
  }
  float* op = out + (size_t)which * NQ + ((size_t)b * C2 + o0) * P2 + p;
  op[0] = a0; op[P2] = a1; op[2 * P2] = a2; op[3 * P2] = a3;
}

// ---------------- per-(b,c) attention core ----------------
__global__ __launch_bounds__(256) void attn_core(
    const float* __restrict__ qkv, float* __restrict__ out)
{
  __shared__ __align__(16) float qs[P2], ks[P2], vs[P2];
  __shared__ __align__(16) float As[28][29];
  int c = blockIdx.x, b = blockIdx.y;
  int tid = threadIdx.x;
  size_t base = ((size_t)b * C2 + c) * P2;
  const float* Q = qkv + base;
  const float* K = qkv + NQ + base;
  const float* V = qkv + 2 * NQ + base;
  for (int idx = tid; idx < P2; idx += 256) {
    qs[idx] = Q[idx]; ks[idx] = K[idx]; vs[idx] = V[idx];
  }
  __syncthreads();
  const float scl = 1.0f / sqrtf(28.0f);
  for (int idx = tid; idx < P2; idx += 256) {
    int h = idx / 28, g = idx - 28 * h;
    float s = 0.f;
    #pragma unroll
    for (int ww = 0; ww < 28; ww++) s = fmaf(qs[h * 28 + ww], ks[g * 28 + ww], s);
    As[h][g] = s * scl;
  }
  __syncthreads();
  if (tid < 28) {
    float m = -1e30f;
    #pragma unroll
    for (int g = 0; g < 28; g++) m = fmaxf(m, As[tid][g]);
    float sum = 0.f;
    #pragma unroll
    for (int g = 0; g < 28; g++) {
      float e = expf(As[tid][g] - m);
      As[tid][g] = e;
      sum += e;
    }
    float r = 1.0f / sum;
    #pragma unroll
    for (int g = 0; g < 28; g++) As[tid][g] *= r;
  }
  __syncthreads();
  for (int idx = tid; idx < P2; idx += 256) {
    int h = idx / 28, ww = idx - 28 * h;
    float s = 0.f;
    #pragma unroll
    for (int g = 0; g < 28; g++) s = fmaf(As[h][g], vs[g * 28 + ww], s);
    out[base + idx] = s;
  }
}

// ---------------- 1x1 conv 192->192 + bias (attention o-proj) ----------------
__global__ __launch_bounds__(256) void pw192(
    const float* __restrict__ x, const float* __restrict__ w,
    const float* __restrict__ bias, float* __restrict__ out)
{
  int p = blockIdx.x * 256 + threadIdx.x;
  if (p >= P2) return;
  int o0 = blockIdx.y * 4;
  int b = blockIdx.z;
  const float* xp = x + (size_t)b * C2 * P2 + p;
  const float* wp = w + (size_t)o0 * C2;
  float a0 = bias[o0 + 0], a1 = bias[o0 + 1], a2 = bias[o0 + 2], a3 = bias[o0 + 3];
  #pragma unroll 8
  for (int c = 0; c < C2; c++) {
    float xv = xp[(size_t)c * P2];
    a0 = fmaf(wp[c], xv, a0);
    a1 = fmaf(wp[C2 + c], xv, a1);
    a2 = fmaf(wp[2 * C2 + c], xv, a2);
    a3 = fmaf(wp[3 * C2 + c], xv, a3);
  }
  float* op = out + ((size_t)b * C2 + o0) * P2 + p;
  op[0] = a0; op[P2] = a1; op[2 * P2] = a2; op[3 * P2] = a3;
}

// ---------------- concat + 1x1 conv 384->192 + BN + ReLU ----------------
__global__ __launch_bounds__(256) void cov_bnrelu(
    const float* __restrict__ fo, const float* __restrict__ bo,
    const float* __restrict__ w, const float* __restrict__ g,
    const float* __restrict__ be, float* __restrict__ out)
{
  int p = blockIdx.x * 256 + threadIdx.x;
  if (p >= P2) return;
  int o0 = blockIdx.y * 4;
  int b = blockIdx.z;
  float a[4] = {0.f, 0.f, 0.f, 0.f};
  const float* wp = w + (size_t)o0 * 384;
  const float* xp = fo + (size_t)b * C2 * P2 + p;
  #pragma unroll 8
  for (int c = 0; c < C2; c++) {
    float xv = xp[(size_t)c * P2];
    #pragma unroll
    for (int oo = 0; oo < 4; oo++) a[oo] = fmaf(wp[oo * 384 + c], xv, a[oo]);
  }
  xp = bo + (size_t)b * C2 * P2 + p;
  #pragma unroll 8
  for (int c = 0; c < C2; c++) {
    float xv = xp[(size_t)c * P2];
    #pragma unroll
    for (int oo = 0; oo < 4; oo++) a[oo] = fmaf(wp[oo * 384 + 192 + c], xv, a[oo]);
  }
  const float inv = 1.0f / sqrtf(1.0f + 1e-5f);
  #pragma unroll
  for (int oo = 0; oo < 4; oo++) {
    int o = o0 + oo;
    out[((size_t)b * C2 + o) * P2 + p] = fmaxf(a[oo] * (g[o] * inv) + be[o], 0.0f);
  }
}

extern "C" void kernel_launch(void* const* d_in, const int* in_sizes, int n_in,
                              void* d_out, int out_size, void* d_ws, size_t ws_size,
                              hipStream_t stream) {
  (void)in_sizes; (void)n_in; (void)out_size;
  const float* face = (const float*)d_in[0];
  const float* body = (const float*)d_in[1];
  const float* f_w1 = (const float*)d_in[2];
  const float* f_w23 = (const float*)d_in[3];
  const float* f_bn = (const float*)d_in[4];
  const float* f_pw = (const float*)d_in[5];
  const float* f_pb = (const float*)d_in[6];
  const float* b_w1 = (const float*)d_in[7];
  const float* b_w23 = (const float*)d_in[8];
  const float* b_bn = (const float*)d_in[9];
  const float* b_pw = (const float*)d_in[10];
  const float* b_pb = (const float*)d_in[11];
  const float* a1_qkv_w = (const float*)d_in[12];
  const float* a1_qkv_b = (const float*)d_in[13];
  const float* a1_o_w = (const float*)d_in[14];
  const float* a1_o_b = (const float*)d_in[15];
  const float* a2_qkv_w = (const float*)d_in[16];
  const float* a2_qkv_b = (const float*)d_in[17];
  const float* a2_o_w = (const float*)d_in[18];
  const float* a2_o_b = (const float*)d_in[19];
  const float* cov_w = (const float*)d_in[20];
  const float* cov_g = (const float*)d_in[21];
  const float* cov_b = (const float*)d_in[22];
  float* out = (float*)d_out;

  // ---- workspace budget: largest stem batch-chunk that fits ws_size ----
  size_t availF = ws_size / sizeof(float);
  int ck = 2;  // floor: 77 MB
  for (int cand = 16; cand >= 4; cand >>= 1) {
    size_t bigF = 2 * (size_t)cand * CHW;
    if (bigF < 6 * NQ) bigF = 6 * NQ;
    if (2 * NQ + bigF <= availF) { ck = cand; break; }
  }

  float* ws = (float*)d_ws;
  float* embf = ws;
  float* embb = ws + NQ;
  float* big  = ws + 2 * NQ;
  float* sb0 = big;
  float* sb1 = big + (size_t)ck * CHW;
  float* qkv = big;
  float* att = big + 3 * NQ;
  float* fo  = big + 4 * NQ;
  float* bo  = big + 5 * NQ;

  dim3 blk2(16, 16);

  // --- face patch embed (chunked over batch) ---
  for (int c0 = 0; c0 < BATCH; c0 += ck) {
    const float* xin = face + (size_t)c0 * 3 * H1 * H1;
    conv7_bnrelu<<<dim3(14, 14, ck * 16), blk2, 0, stream>>>(xin, f_w1, f_bn, sb0);
    conv3_mfma<<<dim3(7, 28, ck), 256, 0, stream>>>(sb0, f_w23, f_bn + 128, sb1);
    conv3_mfma<<<dim3(7, 28, ck), 256, 0, stream>>>(sb1, f_w23 + 36864, f_bn + 256, sb0);
    proj8_gemm<<<dim3(13, 3, ck), blk2, 0, stream>>>(sb0, f_pw, f_pb, embf + (size_t)c0 * C2 * P2);
  }

  // --- body patch embed (chunked over batch) ---
  for (int c0 = 0; c0 < BATCH; c0 += ck) {
    const float* xin = body + (size_t)c0 * 3 * H1 * H1;
    conv7_bnrelu<<<dim3(14, 14, ck * 16), blk2, 0, stream>>>(xin, b_w1, b_bn, sb0);
    conv3_mfma<<<dim3(7, 28, ck), 256, 0, stream>>>(sb0, b_w23, b_bn + 128, sb1);
    conv3_mfma<<<dim3(7, 28, ck), 256, 0, stream>>>(sb1, b_w23 + 36864, b_bn + 256, sb0);
    proj8_gemm<<<dim3(13, 3, ck), blk2, 0, stream>>>(sb0, b_pw, b_pb, embb + (size_t)c0 * C2 * P2);
  }

  // --- attention 1: q from face-embed, k/v from body-embed ---
  qkv192<<<dim3(4, 144, BATCH), 256, 0, stream>>>(embf, embb, a1_qkv_w, a1_qkv_b, qkv);
  attn_core<<<dim3(C2, BATCH), 256, 0, stream>>>(qkv, att);
  pw192<<<dim3(4, 48, BATCH), 256, 0, stream>>>(att, a1_o_w, a1_o_b, fo);

  // --- attention 2: q from body-embed, k/v from face-embed ---
  qkv192<<<dim3(4, 144, BATCH), 256, 0, stream>>>(embb, embf, a2_qkv_w, a2_qkv_b, qkv);
  attn_core<<<dim3(C2, BATCH), 256, 0, stream>>>(qkv, att);
  pw192<<<dim3(4, 48, BATCH), 256, 0, stream>>>(att, a2_o_w, a2_o_b, bo);

  // --- concat + cov 1x1 + BN + ReLU ---
  cov_bnrelu<<<dim3(4, 48, BATCH), 256, 0, stream>>>(fo, bo, cov_w, cov_g, cov_b, out);
}

// Round 8
// 3960.230 us; speedup vs baseline: 3.9931x; 1.6284x over previous
//
#include <hip/hip_runtime.h>
#include <hip/hip_bf16.h>
#include <math.h>

#define BATCH 16
#define H1 224
#define C1 64
#define HP 28
#define P2 784            // 28*28
#define C2 192
#define NQ ((size_t)BATCH*C2*P2)       // 2408448
#define CHW ((size_t)C1*H1*H1)         // 3211264 floats per image

typedef __attribute__((ext_vector_type(8))) short short8;
typedef __attribute__((ext_vector_type(4))) short s16x4;
typedef __attribute__((ext_vector_type(4))) float f32x4;

__device__ __forceinline__ ushort f2bf(float v) {
  __hip_bfloat16 h = __float2bfloat16(v);
  return *(ushort*)&h;
}

// ---------------- conv 7x7 pad3 (3->64) + BN + ReLU, bf16 MFMA ----------------
// grid (7, 14, ck), block 256 (4 waves).
// K = 7dy x (7dx x 4ich-padded) = 7 MFMA K=32 steps (k=dx*4+i, i=3 & dx=7 zero).
// Input LDS: [22 rows][40 cols x 4 ich] FULLY staged (cols 38,39 zero) so every
//   LDS element read is written in-call (round-7 post-timing fix: col-38 reads
//   hit uninit LDS; NaN garbage x zero-weight -> NaN -> ReLU -> silent zeros).
// Weights LDS: [64 och][232] (dy*32+k), och stride 232 (= 29x16B): 2-way max.
// Block tile 64 och x (16 rows x 32 cols); wave = 4 rows; 4 m-frags x 8 n-frags.
__global__ __launch_bounds__(256) void conv7_mfma(
    const float* __restrict__ x, const float* __restrict__ w,
    const float* __restrict__ bn, float* __restrict__ out)
{
  __shared__ ushort in_lds[22 * 160];   //  7040 B
  __shared__ ushort w_lds[64 * 232];    // 29696 B
  int tid = threadIdx.x;
  int wv = tid >> 6, lane = tid & 63;
  int l15 = lane & 15, q = lane >> 4;
  int x0 = blockIdx.x * 32, y0 = blockIdx.y * 16;
  int b = blockIdx.z;

  // --- stage input: 22 rows x 40 cols x 4 ich (i=3 / col>=38 / OOB -> zero) ---
  for (int k = tid; k < 3520; k += 256) {
    int i = k & 3;
    int t = k >> 2;
    int col = t % 40, row = t / 40;
    int gy = y0 - 3 + row, gx = x0 - 3 + col;
    float v = 0.0f;
    if (i < 3 && col < 38 && gy >= 0 && gy < H1 && gx >= 0 && gx < H1)
      v = x[((size_t)(b * 3 + i) * H1 + gy) * H1 + gx];
    in_lds[row * 160 + col * 4 + i] = f2bf(v);
  }
  // --- stage weights: 64 och x 7 dy x 32 k  (k=dx*4+i; i=3 or dx=7 -> 0) ---
  for (int k = tid; k < 14336; k += 256) {
    int och = k / 224;
    int rem = k - och * 224;
    int dy = rem >> 5, kk = rem & 31;
    int dx = kk >> 2, i = kk & 3;
    float v = 0.0f;
    if (i < 3 && dx < 7) v = w[och * 147 + i * 49 + dy * 7 + dx];
    w_lds[och * 232 + dy * 32 + kk] = f2bf(v);
  }
  __syncthreads();

  f32x4 acc[4][8];
  #pragma unroll
  for (int m = 0; m < 4; m++)
    #pragma unroll
    for (int n = 0; n < 8; n++) acc[m][n] = (f32x4){0.f, 0.f, 0.f, 0.f};

  #pragma unroll
  for (int dy = 0; dy < 7; dy++) {
    short8 afr[4];
    #pragma unroll
    for (int m = 0; m < 4; m++)
      afr[m] = *(const short8*)&w_lds[(m * 16 + l15) * 232 + dy * 32 + q * 8];
    #pragma unroll
    for (int n = 0; n < 8; n++) {
      int r = 4 * wv + (n >> 1) + dy;
      int c = (n & 1) * 16 + l15;
      int e = r * 160 + c * 4 + q * 8;
      s16x4 lo = *(const s16x4*)&in_lds[e];
      s16x4 hi = *(const s16x4*)&in_lds[e + 4];
      short8 bfr = __builtin_shufflevector(lo, hi, 0, 1, 2, 3, 4, 5, 6, 7);
      #pragma unroll
      for (int m = 0; m < 4; m++)
        acc[m][n] = __builtin_amdgcn_mfma_f32_16x16x32_bf16(
            afr[m], bfr, acc[m][n], 0, 0, 0);
    }
  }

  // --- epilogue: BN + ReLU (D: col=lane&15 -> px, row=q*4+j -> och) ---
  const float inv = 1.0f / sqrtf(1.0f + 1e-5f);
  #pragma unroll
  for (int m = 0; m < 4; m++) {
    #pragma unroll
    for (int n = 0; n < 8; n++) {
      int py = y0 + 4 * wv + (n >> 1);
      int px = x0 + (n & 1) * 16 + l15;
      #pragma unroll
      for (int j = 0; j < 4; j++) {
        int och = m * 16 + q * 4 + j;
        float sc = bn[och] * inv, be = bn[64 + och];
        float v = fmaxf(acc[m][n][j] * sc + be, 0.0f);
        out[((size_t)(b * C1 + och) * H1 + py) * H1 + px] = v;
      }
    }
  }
}

// ---------------- conv 3x3 pad1 (64->64) + BN + ReLU, bf16 MFMA ----------------
// grid (7, 28, ck), block 256 (4 waves).
__global__ __launch_bounds__(256) void conv3_mfma(
    const float* __restrict__ x, const float* __restrict__ w,
    const float* __restrict__ bn, float* __restrict__ out)
{
  __shared__ ushort in_lds[10][34][40];  // [row][col][ich] 27200 B
  __shared__ ushort w_lds[64][9][40];    // [och][tap][ich] 46080 B
  int tid = threadIdx.x;
  int wv = tid >> 6, lane = tid & 63;
  int l15 = lane & 15, q = lane >> 4;
  int x0 = blockIdx.x * 32, y0 = blockIdx.y * 8;
  int b = blockIdx.z;

  f32x4 acc[4][4];
  #pragma unroll
  for (int m = 0; m < 4; m++)
    #pragma unroll
    for (int n = 0; n < 4; n++) acc[m][n] = (f32x4){0.f, 0.f, 0.f, 0.f};

  for (int ic = 0; ic < 2; ic++) {
    int ich0 = ic * 32;
    __syncthreads();
    for (int k = tid; k < 10880; k += 256) {
      int c = k % 34;
      int t = k / 34;
      int r = t % 10;
      int i = t / 10;
      int gy = y0 - 1 + r, gx = x0 - 1 + c;
      float v = 0.0f;
      if (gy >= 0 && gy < H1 && gx >= 0 && gx < H1)
        v = x[((size_t)(b * C1 + ich0 + i) * H1 + gy) * H1 + gx];
      in_lds[r][c][i] = f2bf(v);
    }
    for (int k = tid; k < 18432; k += 256) {
      int o = k / 288;
      int rem = k - o * 288;
      int i = rem / 9;
      int tap = rem - i * 9;
      float v = w[(size_t)o * 576 + (size_t)(ich0 + i) * 9 + tap];
      w_lds[o][tap][i] = f2bf(v);
    }
    __syncthreads();
    #pragma unroll
    for (int dy = 0; dy < 3; dy++) {
      #pragma unroll
      for (int dx = 0; dx < 3; dx++) {
        int tap = dy * 3 + dx;
        short8 afr[4];
        #pragma unroll
        for (int m = 0; m < 4; m++)
          afr[m] = *(const short8*)&w_lds[m * 16 + l15][tap][q * 8];
        short8 bfr[4];
        #pragma unroll
        for (int n = 0; n < 4; n++) {
          int r = 2 * wv + (n >> 1) + dy;
          int c = (n & 1) * 16 + l15 + dx;
          bfr[n] = *(const short8*)&in_lds[r][c][q * 8];
        }
        #pragma unroll
        for (int m = 0; m < 4; m++)
          #pragma unroll
          for (int n = 0; n < 4; n++)
            acc[m][n] = __builtin_amdgcn_mfma_f32_16x16x32_bf16(
                afr[m], bfr[n], acc[m][n], 0, 0, 0);
      }
    }
  }
  const float inv = 1.0f / sqrtf(1.0f + 1e-5f);
  #pragma unroll
  for (int m = 0; m < 4; m++) {
    #pragma unroll
    for (int n = 0; n < 4; n++) {
      int py = y0 + 2 * wv + (n >> 1);
      int px = x0 + (n & 1) * 16 + l15;
      #pragma unroll
      for (int j = 0; j < 4; j++) {
        int och = m * 16 + q * 4 + j;
        float sc = bn[och] * inv, be = bn[64 + och];
        float v = fmaxf(acc[m][n][j] * sc + be, 0.0f);
        out[((size_t)(b * C1 + och) * H1 + py) * H1 + px] = v;
      }
    }
  }
}

// ---------------- proj conv 8x8 stride 8 (64->192) + bias, as tiled GEMM ----
#define PJS 68  // LDS row stride (floats)
__global__ __launch_bounds__(256) void proj8_gemm(
    const float* __restrict__ x, const float* __restrict__ w,
    const float* __restrict__ bias, float* __restrict__ out)
{
  __shared__ __align__(16) float As[64 * PJS];
  __shared__ __align__(16) float Bs[64 * PJS];
  int tx = threadIdx.x, ty = threadIdx.y;
  int tid = ty * 16 + tx;
  int p0 = blockIdx.x * 64;
  int o0 = blockIdx.y * 64;
  int b = blockIdx.z;
  float acc[4][4];
  #pragma unroll
  for (int pi = 0; pi < 4; pi++)
    #pragma unroll
    for (int oi = 0; oi < 4; oi++) acc[pi][oi] = 0.0f;

  for (int i = 0; i < 64; i++) {
    __syncthreads();
    #pragma unroll
    for (int qq = 0; qq < 4; qq++) {
      int f = qq * 256 + tid;
      int oo = f >> 4, t4 = f & 15;
      const float4 wv = *(const float4*)(w + ((size_t)(o0 + oo) * 4096) + i * 64 + t4 * 4);
      *(float4*)&Bs[oo * PJS + t4 * 4] = wv;
    }
    #pragma unroll
    for (int qq = 0; qq < 4; qq++) {
      int f = qq * 256 + tid;
      int pp = f >> 4, dy = (f >> 1) & 7, half = f & 1;
      int p = p0 + pp;
      float4 xv = make_float4(0.f, 0.f, 0.f, 0.f);
      if (p < P2) {
        int py = p / 28, px = p - 28 * py;
        xv = *(const float4*)(x + ((size_t)(b * C1 + i) * H1 + 8 * py + dy) * H1 + 8 * px + half * 4);
      }
      *(float4*)&As[pp * PJS + dy * 8 + half * 4] = xv;
    }
    __syncthreads();
    #pragma unroll 4
    for (int t4 = 0; t4 < 16; t4++) {
      float4 av[4], bv[4];
      #pragma unroll
      for (int pi = 0; pi < 4; pi++)
        av[pi] = *(const float4*)&As[(ty + 16 * pi) * PJS + t4 * 4];
      #pragma unroll
      for (int oi = 0; oi < 4; oi++)
        bv[oi] = *(const float4*)&Bs[(tx + 16 * oi) * PJS + t4 * 4];
      #pragma unroll
      for (int pi = 0; pi < 4; pi++)
        #pragma unroll
        for (int oi = 0; oi < 4; oi++) {
          float s = acc[pi][oi];
          s = fmaf(av[pi].x, bv[oi].x, s);
          s = fmaf(av[pi].y, bv[oi].y, s);
          s = fmaf(av[pi].z, bv[oi].z, s);
          s = fmaf(av[pi].w, bv[oi].w, s);
          acc[pi][oi] = s;
        }
    }
  }
  #pragma unroll
  for (int pi = 0; pi < 4; pi++) {
    int p = p0 + ty + 16 * pi;
    if (p >= P2) continue;
    #pragma unroll
    for (int oi = 0; oi < 4; oi++) {
      int o = o0 + tx + 16 * oi;
      out[((size_t)(b * C2 + o)) * P2 + p] = acc[pi][oi] + bias[o];
    }
  }
}

// ---------------- fused q/k/v 1x1 projections ----------------
__global__ __launch_bounds__(256) void qkv192(
    const float* __restrict__ xq, const float* __restrict__ xkv,
    const float* __restrict__ w, const float* __restrict__ bias,
    float* __restrict__ out)
{
  int p = blockIdx.x * 256 + threadIdx.x;
  if (p >= P2) return;
  int by = blockIdx.y;
  int which = by / 48, o0 = (by % 48) * 4;
  int b = blockIdx.z;
  const float* xp = (which == 0 ? xq : xkv) + (size_t)b * C2 * P2 + p;
  const float* wp = w + (size_t)which * C2 * C2 + (size_t)o0 * C2;
  float a0 = bias[which * C2 + o0 + 0];
  float a1 = bias[which * C2 + o0 + 1];
  float a2 = bias[which * C2 + o0 + 2];
  float a3 = bias[which * C2 + o0 + 3];
  #pragma unroll 8
  for (int c = 0; c < C2; c++) {
    float xv = xp[(size_t)c * P2];
    a0 = fmaf(wp[c], xv, a0);
    a1 = fmaf(wp[C2 + c], xv, a1);
    a2 = fmaf(wp[2 * C2 + c], xv, a2);
    a3 = fmaf(wp[3 * C2 + c], xv, a3);
  }
  float* op = out + (size_t)which * NQ + ((size_t)b * C2 + o0) * P2 + p;
  op[0] = a0; op[P2] = a1; op[2 * P2] = a2; op[3 * P2] = a3;
}

// ---------------- per-(b,c) attention core ----------------
__global__ __launch_bounds__(256) void attn_core(
    const float* __restrict__ qkv, float* __restrict__ out)
{
  __shared__ __align__(16) float qs[P2], ks[P2], vs[P2];
  __shared__ __align__(16) float As[28][29];
  int c = blockIdx.x, b = blockIdx.y;
  int tid = threadIdx.x;
  size_t base = ((size_t)b * C2 + c) * P2;
  const float* Q = qkv + base;
  const float* K = qkv + NQ + base;
  const float* V = qkv + 2 * NQ + base;
  for (int idx = tid; idx < P2; idx += 256) {
    qs[idx] = Q[idx]; ks[idx] = K[idx]; vs[idx] = V[idx];
  }
  __syncthreads();
  const float scl = 1.0f / sqrtf(28.0f);
  for (int idx = tid; idx < P2; idx += 256) {
    int h = idx / 28, g = idx - 28 * h;
    float s = 0.f;
    #pragma unroll
    for (int ww = 0; ww < 28; ww++) s = fmaf(qs[h * 28 + ww], ks[g * 28 + ww], s);
    As[h][g] = s * scl;
  }
  __syncthreads();
  if (tid < 28) {
    float m = -1e30f;
    #pragma unroll
    for (int g = 0; g < 28; g++) m = fmaxf(m, As[tid][g]);
    float sum = 0.f;
    #pragma unroll
    for (int g = 0; g < 28; g++) {
      float e = expf(As[tid][g] - m);
      As[tid][g] = e;
      sum += e;
    }
    float r = 1.0f / sum;
    #pragma unroll
    for (int g = 0; g < 28; g++) As[tid][g] *= r;
  }
  __syncthreads();
  for (int idx = tid; idx < P2; idx += 256) {
    int h = idx / 28, ww = idx - 28 * h;
    float s = 0.f;
    #pragma unroll
    for (int g = 0; g < 28; g++) s = fmaf(As[h][g], vs[g * 28 + ww], s);
    out[base + idx] = s;
  }
}

// ---------------- 1x1 conv 192->192 + bias (attention o-proj) ----------------
__global__ __launch_bounds__(256) void pw192(
    const float* __restrict__ x, const float* __restrict__ w,
    const float* __restrict__ bias, float* __restrict__ out)
{
  int p = blockIdx.x * 256 + threadIdx.x;
  if (p >= P2) return;
  int o0 = blockIdx.y * 4;
  int b = blockIdx.z;
  const float* xp = x + (size_t)b * C2 * P2 + p;
  const float* wp = w + (size_t)o0 * C2;
  float a0 = bias[o0 + 0], a1 = bias[o0 + 1], a2 = bias[o0 + 2], a3 = bias[o0 + 3];
  #pragma unroll 8
  for (int c = 0; c < C2; c++) {
    float xv = xp[(size_t)c * P2];
    a0 = fmaf(wp[c], xv, a0);
    a1 = fmaf(wp[C2 + c], xv, a1);
    a2 = fmaf(wp[2 * C2 + c], xv, a2);
    a3 = fmaf(wp[3 * C2 + c], xv, a3);
  }
  float* op = out + ((size_t)b * C2 + o0) * P2 + p;
  op[0] = a0; op[P2] = a1; op[2 * P2] = a2; op[3 * P2] = a3;
}

// ---------------- concat + 1x1 conv 384->192 + BN + ReLU ----------------
__global__ __launch_bounds__(256) void cov_bnrelu(
    const float* __restrict__ fo, const float* __restrict__ bo,
    const float* __restrict__ w, const float* __restrict__ g,
    const float* __restrict__ be, float* __restrict__ out)
{
  int p = blockIdx.x * 256 + threadIdx.x;
  if (p >= P2) return;
  int o0 = blockIdx.y * 4;
  int b = blockIdx.z;
  float a[4] = {0.f, 0.f, 0.f, 0.f};
  const float* wp = w + (size_t)o0 * 384;
  const float* xp = fo + (size_t)b * C2 * P2 + p;
  #pragma unroll 8
  for (int c = 0; c < C2; c++) {
    float xv = xp[(size_t)c * P2];
    #pragma unroll
    for (int oo = 0; oo < 4; oo++) a[oo] = fmaf(wp[oo * 384 + c], xv, a[oo]);
  }
  xp = bo + (size_t)b * C2 * P2 + p;
  #pragma unroll 8
  for (int c = 0; c < C2; c++) {
    float xv = xp[(size_t)c * P2];
    #pragma unroll
    for (int oo = 0; oo < 4; oo++) a[oo] = fmaf(wp[oo * 384 + 192 + c], xv, a[oo]);
  }
  const float inv = 1.0f / sqrtf(1.0f + 1e-5f);
  #pragma unroll
  for (int oo = 0; oo < 4; oo++) {
    int o = o0 + oo;
    out[((size_t)b * C2 + o) * P2 + p] = fmaxf(a[oo] * (g[o] * inv) + be[o], 0.0f);
  }
}

extern "C" void kernel_launch(void* const* d_in, const int* in_sizes, int n_in,
                              void* d_out, int out_size, void* d_ws, size_t ws_size,
                              hipStream_t stream) {
  (void)in_sizes; (void)n_in; (void)out_size;
  const float* face = (const float*)d_in[0];
  const float* body = (const float*)d_in[1];
  const float* f_w1 = (const float*)d_in[2];
  const float* f_w23 = (const float*)d_in[3];
  const float* f_bn = (const float*)d_in[4];
  const float* f_pw = (const float*)d_in[5];
  const float* f_pb = (const float*)d_in[6];
  const float* b_w1 = (const float*)d_in[7];
  const float* b_w23 = (const float*)d_in[8];
  const float* b_bn = (const float*)d_in[9];
  const float* b_pw = (const float*)d_in[10];
  const float* b_pb = (const float*)d_in[11];
  const float* a1_qkv_w = (const float*)d_in[12];
  const float* a1_qkv_b = (const float*)d_in[13];
  const float* a1_o_w = (const float*)d_in[14];
  const float* a1_o_b = (const float*)d_in[15];
  const float* a2_qkv_w = (const float*)d_in[16];
  const float* a2_qkv_b = (const float*)d_in[17];
  const float* a2_o_w = (const float*)d_in[18];
  const float* a2_o_b = (const float*)d_in[19];
  const float* cov_w = (const float*)d_in[20];
  const float* cov_g = (const float*)d_in[21];
  const float* cov_b = (const float*)d_in[22];
  float* out = (float*)d_out;

  // ---- workspace budget: largest stem batch-chunk that fits ws_size ----
  size_t availF = ws_size / sizeof(float);
  int ck = 2;  // floor: 77 MB
  for (int cand = 16; cand >= 4; cand >>= 1) {
    size_t bigF = 2 * (size_t)cand * CHW;
    if (bigF < 6 * NQ) bigF = 6 * NQ;
    if (2 * NQ + bigF <= availF) { ck = cand; break; }
  }

  float* ws = (float*)d_ws;
  float* embf = ws;
  float* embb = ws + NQ;
  float* big  = ws + 2 * NQ;
  float* sb0 = big;
  float* sb1 = big + (size_t)ck * CHW;
  float* qkv = big;
  float* att = big + 3 * NQ;
  float* fo  = big + 4 * NQ;
  float* bo  = big + 5 * NQ;

  dim3 blk2(16, 16);

  // --- face patch embed (chunked over batch) ---
  for (int c0 = 0; c0 < BATCH; c0 += ck) {
    const float* xin = face + (size_t)c0 * 3 * H1 * H1;
    conv7_mfma<<<dim3(7, 14, ck), 256, 0, stream>>>(xin, f_w1, f_bn, sb0);
    conv3_mfma<<<dim3(7, 28, ck), 256, 0, stream>>>(sb0, f_w23, f_bn + 128, sb1);
    conv3_mfma<<<dim3(7, 28, ck), 256, 0, stream>>>(sb1, f_w23 + 36864, f_bn + 256, sb0);
    proj8_gemm<<<dim3(13, 3, ck), blk2, 0, stream>>>(sb0, f_pw, f_pb, embf + (size_t)c0 * C2 * P2);
  }

  // --- body patch embed (chunked over batch) ---
  for (int c0 = 0; c0 < BATCH; c0 += ck) {
    const float* xin = body + (size_t)c0 * 3 * H1 * H1;
    conv7_mfma<<<dim3(7, 14, ck), 256, 0, stream>>>(xin, b_w1, b_bn, sb0);
    conv3_mfma<<<dim3(7, 28, ck), 256, 0, stream>>>(sb0, b_w23, b_bn + 128, sb1);
    conv3_mfma<<<dim3(7, 28, ck), 256, 0, stream>>>(sb1, b_w23 + 36864, b_bn + 256, sb0);
    proj8_gemm<<<dim3(13, 3, ck), blk2, 0, stream>>>(sb0, b_pw, b_pb, embb + (size_t)c0 * C2 * P2);
  }

  // --- attention 1: q from face-embed, k/v from body-embed ---
  qkv192<<<dim3(4, 144, BATCH), 256, 0, stream>>>(embf, embb, a1_qkv_w, a1_qkv_b, qkv);
  attn_core<<<dim3(C2, BATCH), 256, 0, stream>>>(qkv, att);
  pw192<<<dim3(4, 48, BATCH), 256, 0, stream>>>(att, a1_o_w, a1_o_b, fo);

  // --- attention 2: q from body-embed, k/v from face-embed ---
  qkv192<<<dim3(4, 144, BATCH), 256, 0, stream>>>(embb, embf, a2_qkv_w, a2_qkv_b, qkv);
  attn_core<<<dim3(C2, BATCH), 256, 0, stream>>>(qkv, att);
  pw192<<<dim3(4, 48, BATCH), 256, 0, stream>>>(att, a2_o_w, a2_o_b, bo);

  // --- concat + cov 1x1 + BN + ReLU ---
  cov_bnrelu<<<dim3(4, 48, BATCH), 256, 0, stream>>>(fo, bo, cov_w, cov_g, cov_b, out);
}

// Round 11
// 3405.101 us; speedup vs baseline: 4.6441x; 1.1630x over previous
//
#include <hip/hip_runtime.h>
#include <hip/hip_bf16.h>
#include <math.h>

#define BATCH 16
#define H1 224
#define C1 64
#define HP 28
#define P2 784            // 28*28
#define C2 192
#define NQ ((size_t)BATCH*C2*P2)       // 2408448
#define CHW ((size_t)C1*H1*H1)         // 3211264 floats per image

typedef __attribute__((ext_vector_type(8))) short short8;
typedef __attribute__((ext_vector_type(4))) short s16x4;
typedef __attribute__((ext_vector_type(4))) float f32x4;

__device__ __forceinline__ ushort f2bf(float v) {
  __hip_bfloat16 h = __float2bfloat16(v);
  return *(ushort*)&h;
}

// ---------------- conv 7x7 pad3 (3->64) + BN + ReLU, bf16 MFMA ----------------
// grid (7, 14, ck), block 256 (4 waves).
__global__ __launch_bounds__(256) void conv7_mfma(
    const float* __restrict__ x, const float* __restrict__ w,
    const float* __restrict__ bn, float* __restrict__ out)
{
  __shared__ ushort in_lds[22 * 160];   //  7040 B
  __shared__ ushort w_lds[64 * 232];    // 29696 B
  int tid = threadIdx.x;
  int wv = tid >> 6, lane = tid & 63;
  int l15 = lane & 15, q = lane >> 4;
  int x0 = blockIdx.x * 32, y0 = blockIdx.y * 16;
  int b = blockIdx.z;

  // --- stage input: 22 rows x 40 cols x 4 ich (i=3 / col>=38 / OOB -> zero) ---
  for (int k = tid; k < 3520; k += 256) {
    int i = k & 3;
    int t = k >> 2;
    int col = t % 40, row = t / 40;
    int gy = y0 - 3 + row, gx = x0 - 3 + col;
    float v = 0.0f;
    if (i < 3 && col < 38 && gy >= 0 && gy < H1 && gx >= 0 && gx < H1)
      v = x[((size_t)(b * 3 + i) * H1 + gy) * H1 + gx];
    in_lds[row * 160 + col * 4 + i] = f2bf(v);
  }
  // --- stage weights: 64 och x 7 dy x 32 k  (k=dx*4+i; i=3 or dx=7 -> 0) ---
  for (int k = tid; k < 14336; k += 256) {
    int och = k / 224;
    int rem = k - och * 224;
    int dy = rem >> 5, kk = rem & 31;
    int dx = kk >> 2, i = kk & 3;
    float v = 0.0f;
    if (i < 3 && dx < 7) v = w[och * 147 + i * 49 + dy * 7 + dx];
    w_lds[och * 232 + dy * 32 + kk] = f2bf(v);
  }
  __syncthreads();

  f32x4 acc[4][8];
  #pragma unroll
  for (int m = 0; m < 4; m++)
    #pragma unroll
    for (int n = 0; n < 8; n++) acc[m][n] = (f32x4){0.f, 0.f, 0.f, 0.f};

  #pragma unroll
  for (int dy = 0; dy < 7; dy++) {
    short8 afr[4];
    #pragma unroll
    for (int m = 0; m < 4; m++)
      afr[m] = *(const short8*)&w_lds[(m * 16 + l15) * 232 + dy * 32 + q * 8];
    #pragma unroll
    for (int n = 0; n < 8; n++) {
      int r = 4 * wv + (n >> 1) + dy;
      int c = (n & 1) * 16 + l15;
      int e = r * 160 + c * 4 + q * 8;
      s16x4 lo = *(const s16x4*)&in_lds[e];
      s16x4 hi = *(const s16x4*)&in_lds[e + 4];
      short8 bfr = __builtin_shufflevector(lo, hi, 0, 1, 2, 3, 4, 5, 6, 7);
      #pragma unroll
      for (int m = 0; m < 4; m++)
        acc[m][n] = __builtin_amdgcn_mfma_f32_16x16x32_bf16(
            afr[m], bfr, acc[m][n], 0, 0, 0);
    }
  }

  const float inv = 1.0f / sqrtf(1.0f + 1e-5f);
  #pragma unroll
  for (int m = 0; m < 4; m++) {
    #pragma unroll
    for (int n = 0; n < 8; n++) {
      int py = y0 + 4 * wv + (n >> 1);
      int px = x0 + (n & 1) * 16 + l15;
      #pragma unroll
      for (int j = 0; j < 4; j++) {
        int och = m * 16 + q * 4 + j;
        float sc = bn[och] * inv, be = bn[64 + och];
        float v = fmaxf(acc[m][n][j] * sc + be, 0.0f);
        out[((size_t)(b * C1 + och) * H1 + py) * H1 + px] = v;
      }
    }
  }
}

// ---------------- conv 3x3 pad1 (64->64) + BN + ReLU, bf16 MFMA ----------------
// grid (7, 28, ck), block 256 (4 waves).
__global__ __launch_bounds__(256) void conv3_mfma(
    const float* __restrict__ x, const float* __restrict__ w,
    const float* __restrict__ bn, float* __restrict__ out)
{
  __shared__ ushort in_lds[10][34][40];  // [row][col][ich] 27200 B
  __shared__ ushort w_lds[64][9][40];    // [och][tap][ich] 46080 B
  int tid = threadIdx.x;
  int wv = tid >> 6, lane = tid & 63;
  int l15 = lane & 15, q = lane >> 4;
  int x0 = blockIdx.x * 32, y0 = blockIdx.y * 8;
  int b = blockIdx.z;

  f32x4 acc[4][4];
  #pragma unroll
  for (int m = 0; m < 4; m++)
    #pragma unroll
    for (int n = 0; n < 4; n++) acc[m][n] = (f32x4){0.f, 0.f, 0.f, 0.f};

  for (int ic = 0; ic < 2; ic++) {
    int ich0 = ic * 32;
    __syncthreads();
    for (int k = tid; k < 10880; k += 256) {
      int c = k % 34;
      int t = k / 34;
      int r = t % 10;
      int i = t / 10;
      int gy = y0 - 1 + r, gx = x0 - 1 + c;
      float v = 0.0f;
      if (gy >= 0 && gy < H1 && gx >= 0 && gx < H1)
        v = x[((size_t)(b * C1 + ich0 + i) * H1 + gy) * H1 + gx];
      in_lds[r][c][i] = f2bf(v);
    }
    for (int k = tid; k < 18432; k += 256) {
      int o = k / 288;
      int rem = k - o * 288;
      int i = rem / 9;
      int tap = rem - i * 9;
      float v = w[(size_t)o * 576 + (size_t)(ich0 + i) * 9 + tap];
      w_lds[o][tap][i] = f2bf(v);
    }
    __syncthreads();
    #pragma unroll
    for (int dy = 0; dy < 3; dy++) {
      #pragma unroll
      for (int dx = 0; dx < 3; dx++) {
        int tap = dy * 3 + dx;
        short8 afr[4];
        #pragma unroll
        for (int m = 0; m < 4; m++)
          afr[m] = *(const short8*)&w_lds[m * 16 + l15][tap][q * 8];
        short8 bfr[4];
        #pragma unroll
        for (int n = 0; n < 4; n++) {
          int r = 2 * wv + (n >> 1) + dy;
          int c = (n & 1) * 16 + l15 + dx;
          bfr[n] = *(const short8*)&in_lds[r][c][q * 8];
        }
        #pragma unroll
        for (int m = 0; m < 4; m++)
          #pragma unroll
          for (int n = 0; n < 4; n++)
            acc[m][n] = __builtin_amdgcn_mfma_f32_16x16x32_bf16(
                afr[m], bfr[n], acc[m][n], 0, 0, 0);
      }
    }
  }
  const float inv = 1.0f / sqrtf(1.0f + 1e-5f);
  #pragma unroll
  for (int m = 0; m < 4; m++) {
    #pragma unroll
    for (int n = 0; n < 4; n++) {
      int py = y0 + 2 * wv + (n >> 1);
      int px = x0 + (n & 1) * 16 + l15;
      #pragma unroll
      for (int j = 0; j < 4; j++) {
        int och = m * 16 + q * 4 + j;
        float sc = bn[och] * inv, be = bn[64 + och];
        float v = fmaxf(acc[m][n][j] * sc + be, 0.0f);
        out[((size_t)(b * C1 + och) * H1 + py) * H1 + px] = v;
      }
    }
  }
}

// ---------------- proj conv 8x8 stride 8 (64->192) + bias, bf16 MFMA ----------
// GEMM: out[o,p] = bias[o] + sum_k w[o,k]*patch[p,k], K = 4096 (ich*64+dy*8+dx).
// grid (13, 3, ck), block 256 (4 waves, 2x2 over the 64o x 64p tile), acc[2][2].
// K-loop: 32 rounds of BK=128 (one ich pair; weight rows contiguous in k).
// LDS: a[64][136], b[64][136] bf16 (34816 B -> 4 blocks/CU); 272 B row stride
// -> 2-way bank alias max (free, m136).
__global__ __launch_bounds__(256) void proj8_mfma(
    const float* __restrict__ x, const float* __restrict__ w,
    const float* __restrict__ bias, float* __restrict__ out)
{
  __shared__ ushort a_lds[64 * 136];  // weights [o][k]
  __shared__ ushort b_lds[64 * 136];  // patches [p][k]
  int tid = threadIdx.x;
  int wv = tid >> 6, lane = tid & 63;
  int l15 = lane & 15, q = lane >> 4;
  int wm = wv >> 1, wn = wv & 1;      // 2x2 wave grid over (o,p)
  int p0 = blockIdx.x * 64, o0 = blockIdx.y * 64;
  int b = blockIdx.z;

  f32x4 acc[2][2];
  #pragma unroll
  for (int m = 0; m < 2; m++)
    #pragma unroll
    for (int n = 0; n < 2; n++) acc[m][n] = (f32x4){0.f, 0.f, 0.f, 0.f};

  for (int ic0 = 0; ic0 < 64; ic0 += 2) {
    __syncthreads();
    // --- stage weights: 64 o x 128 k (contiguous in k across the ich pair) ---
    for (int f = tid; f < 2048; f += 256) {
      int oo = f >> 5, r = f & 31;
      const float4 wv4 = *(const float4*)(w + (size_t)(o0 + oo) * 4096 + ic0 * 64 + r * 4);
      ushort* dst = &a_lds[oo * 136 + r * 4];
      dst[0] = f2bf(wv4.x); dst[1] = f2bf(wv4.y);
      dst[2] = f2bf(wv4.z); dst[3] = f2bf(wv4.w);
    }
    // --- stage patches: 64 p x 128 k (k = ic*64 + dy*8 + dx) ---
    for (int f = tid; f < 2048; f += 256) {
      int pp = f >> 5, r = f & 31;
      int ic = r >> 4, t4 = r & 15;
      int dy = t4 >> 1, half = t4 & 1;
      int p = p0 + pp;
      float4 xv = make_float4(0.f, 0.f, 0.f, 0.f);
      if (p < P2) {
        int py = p / 28, px = p - 28 * py;
        xv = *(const float4*)(x + ((size_t)(b * C1 + ic0 + ic) * H1 + 8 * py + dy) * H1 + 8 * px + half * 4);
      }
      ushort* dst = &b_lds[pp * 136 + ic * 64 + dy * 8 + half * 4];
      dst[0] = f2bf(xv.x); dst[1] = f2bf(xv.y);
      dst[2] = f2bf(xv.z); dst[3] = f2bf(xv.w);
    }
    __syncthreads();
    // --- compute: 4 K32 steps x 2m x 2n = 16 MFMA per wave ---
    #pragma unroll
    for (int ks = 0; ks < 4; ks++) {
      short8 afr[2], bfr[2];
      #pragma unroll
      for (int m = 0; m < 2; m++)
        afr[m] = *(const short8*)&a_lds[(wm * 32 + m * 16 + l15) * 136 + ks * 32 + q * 8];
      #pragma unroll
      for (int n = 0; n < 2; n++)
        bfr[n] = *(const short8*)&b_lds[(wn * 32 + n * 16 + l15) * 136 + ks * 32 + q * 8];
      #pragma unroll
      for (int m = 0; m < 2; m++)
        #pragma unroll
        for (int n = 0; n < 2; n++)
          acc[m][n] = __builtin_amdgcn_mfma_f32_16x16x32_bf16(
              afr[m], bfr[n], acc[m][n], 0, 0, 0);
    }
  }
  // --- epilogue: D col=lane&15 -> p, row=q*4+j -> o ---
  #pragma unroll
  for (int m = 0; m < 2; m++) {
    #pragma unroll
    for (int n = 0; n < 2; n++) {
      int p = p0 + wn * 32 + n * 16 + l15;
      if (p >= P2) continue;
      #pragma unroll
      for (int j = 0; j < 4; j++) {
        int o = o0 + wm * 32 + m * 16 + q * 4 + j;
        out[((size_t)(b * C2 + o)) * P2 + p] = acc[m][n][j] + bias[o];
      }
    }
  }
}

// ---------------- fused q/k/v 1x1 projections ----------------
__global__ __launch_bounds__(256) void qkv192(
    const float* __restrict__ xq, const float* __restrict__ xkv,
    const float* __restrict__ w, const float* __restrict__ bias,
    float* __restrict__ out)
{
  int p = blockIdx.x * 256 + threadIdx.x;
  if (p >= P2) return;
  int by = blockIdx.y;
  int which = by / 48, o0 = (by % 48) * 4;
  int b = blockIdx.z;
  const float* xp = (which == 0 ? xq : xkv) + (size_t)b * C2 * P2 + p;
  const float* wp = w + (size_t)which * C2 * C2 + (size_t)o0 * C2;
  float a0 = bias[which * C2 + o0 + 0];
  float a1 = bias[which * C2 + o0 + 1];
  float a2 = bias[which * C2 + o0 + 2];
  float a3 = bias[which * C2 + o0 + 3];
  #pragma unroll 8
  for (int c = 0; c < C2; c++) {
    float xv = xp[(size_t)c * P2];
    a0 = fmaf(wp[c], xv, a0);
    a1 = fmaf(wp[C2 + c], xv, a1);
    a2 = fmaf(wp[2 * C2 + c], xv, a2);
    a3 = fmaf(wp[3 * C2 + c], xv, a3);
  }
  float* op = out + (size_t)which * NQ + ((size_t)b * C2 + o0) * P2 + p;
  op[0] = a0; op[P2] = a1; op[2 * P2] = a2; op[3 * P2] = a3;
}

// ---------------- per-(b,c) attention core ----------------
__global__ __launch_bounds__(256) void attn_core(
    const float* __restrict__ qkv, float* __restrict__ out)
{
  __shared__ __align__(16) float qs[P2], ks[P2], vs[P2];
  __shared__ __align__(16) float As[28][29];
  int c = blockIdx.x, b = blockIdx.y;
  int tid = threadIdx.x;
  size_t base = ((size_t)b * C2 + c) * P2;
  const float* Q = qkv + base;
  const float* K = qkv + NQ + base;
  const float* V = qkv + 2 * NQ + base;
  for (int idx = tid; idx < P2; idx += 256) {
    qs[idx] = Q[idx]; ks[idx] = K[idx]; vs[idx] = V[idx];
  }
  __syncthreads();
  const float scl = 1.0f / sqrtf(28.0f);
  for (int idx = tid; idx < P2; idx += 256) {
    int h = idx / 28, g = idx - 28 * h;
    float s = 0.f;
    #pragma unroll
    for (int ww = 0; ww < 28; ww++) s = fmaf(qs[h * 28 + ww], ks[g * 28 + ww], s);
    As[h][g] = s * scl;
  }
  __syncthreads();
  if (tid < 28) {
    float m = -1e30f;
    #pragma unroll
    for (int g = 0; g < 28; g++) m = fmaxf(m, As[tid][g]);
    float sum = 0.f;
    #pragma unroll
    for (int g = 0; g < 28; g++) {
      float e = expf(As[tid][g] - m);
      As[tid][g] = e;
      sum += e;
    }
    float r = 1.0f / sum;
    #pragma unroll
    for (int g = 0; g < 28; g++) As[tid][g] *= r;
  }
  __syncthreads();
  for (int idx = tid; idx < P2; idx += 256) {
    int h = idx / 28, ww = idx - 28 * h;
    float s = 0.f;
    #pragma unroll
    for (int g = 0; g < 28; g++) s = fmaf(As[h][g], vs[g * 28 + ww], s);
    out[base + idx] = s;
  }
}

// ---------------- 1x1 conv 192->192 + bias (attention o-proj) ----------------
__global__ __launch_bounds__(256) void pw192(
    const float* __restrict__ x, const float* __restrict__ w,
    const float* __restrict__ bias, float* __restrict__ out)
{
  int p = blockIdx.x * 256 + threadIdx.x;
  if (p >= P2) return;
  int o0 = blockIdx.y * 4;
  int b = blockIdx.z;
  const float* xp = x + (size_t)b * C2 * P2 + p;
  const float* wp = w + (size_t)o0 * C2;
  float a0 = bias[o0 + 0], a1 = bias[o0 + 1], a2 = bias[o0 + 2], a3 = bias[o0 + 3];
  #pragma unroll 8
  for (int c = 0; c < C2; c++) {
    float xv = xp[(size_t)c * P2];
    a0 = fmaf(wp[c], xv, a0);
    a1 = fmaf(wp[C2 + c], xv, a1);
    a2 = fmaf(wp[2 * C2 + c], xv, a2);
    a3 = fmaf(wp[3 * C2 + c], xv, a3);
  }
  float* op = out + ((size_t)b * C2 + o0) * P2 + p;
  op[0] = a0; op[P2] = a1; op[2 * P2] = a2; op[3 * P2] = a3;
}

// ---------------- concat + 1x1 conv 384->192 + BN + ReLU ----------------
__global__ __launch_bounds__(256) void cov_bnrelu(
    const float* __restrict__ fo, const float* __restrict__ bo,
    const float* __restrict__ w, const float* __restrict__ g,
    const float* __restrict__ be, float* __restrict__ out)
{
  int p = blockIdx.x * 256 + threadIdx.x;
  if (p >= P2) return;
  int o0 = blockIdx.y * 4;
  int b = blockIdx.z;
  float a[4] = {0.f, 0.f, 0.f, 0.f};
  const float* wp = w + (size_t)o0 * 384;
  const float* xp = fo + (size_t)b * C2 * P2 + p;
  #pragma unroll 8
  for (int c = 0; c < C2; c++) {
    float xv = xp[(size_t)c * P2];
    #pragma unroll
    for (int oo = 0; oo < 4; oo++) a[oo] = fmaf(wp[oo * 384 + c], xv, a[oo]);
  }
  xp = bo + (size_t)b * C2 * P2 + p;
  #pragma unroll 8
  for (int c = 0; c < C2; c++) {
    float xv = xp[(size_t)c * P2];
    #pragma unroll
    for (int oo = 0; oo < 4; oo++) a[oo] = fmaf(wp[oo * 384 + 192 + c], xv, a[oo]);
  }
  const float inv = 1.0f / sqrtf(1.0f + 1e-5f);
  #pragma unroll
  for (int oo = 0; oo < 4; oo++) {
    int o = o0 + oo;
    out[((size_t)b * C2 + o) * P2 + p] = fmaxf(a[oo] * (g[o] * inv) + be[o], 0.0f);
  }
}

extern "C" void kernel_launch(void* const* d_in, const int* in_sizes, int n_in,
                              void* d_out, int out_size, void* d_ws, size_t ws_size,
                              hipStream_t stream) {
  (void)in_sizes; (void)n_in; (void)out_size;
  const float* face = (const float*)d_in[0];
  const float* body = (const float*)d_in[1];
  const float* f_w1 = (const float*)d_in[2];
  const float* f_w23 = (const float*)d_in[3];
  const float* f_bn = (const float*)d_in[4];
  const float* f_pw = (const float*)d_in[5];
  const float* f_pb = (const float*)d_in[6];
  const float* b_w1 = (const float*)d_in[7];
  const float* b_w23 = (const float*)d_in[8];
  const float* b_bn = (const float*)d_in[9];
  const float* b_pw = (const float*)d_in[10];
  const float* b_pb = (const float*)d_in[11];
  const float* a1_qkv_w = (const float*)d_in[12];
  const float* a1_qkv_b = (const float*)d_in[13];
  const float* a1_o_w = (const float*)d_in[14];
  const float* a1_o_b = (const float*)d_in[15];
  const float* a2_qkv_w = (const float*)d_in[16];
  const float* a2_qkv_b = (const float*)d_in[17];
  const float* a2_o_w = (const float*)d_in[18];
  const float* a2_o_b = (const float*)d_in[19];
  const float* cov_w = (const float*)d_in[20];
  const float* cov_g = (const float*)d_in[21];
  const float* cov_b = (const float*)d_in[22];
  float* out = (float*)d_out;

  // ---- workspace budget: largest stem batch-chunk that fits ws_size ----
  size_t availF = ws_size / sizeof(float);
  int ck = 2;  // floor: 77 MB
  for (int cand = 16; cand >= 4; cand >>= 1) {
    size_t bigF = 2 * (size_t)cand * CHW;
    if (bigF < 6 * NQ) bigF = 6 * NQ;
    if (2 * NQ + bigF <= availF) { ck = cand; break; }
  }

  float* ws = (float*)d_ws;
  float* embf = ws;
  float* embb = ws + NQ;
  float* big  = ws + 2 * NQ;
  float* sb0 = big;
  float* sb1 = big + (size_t)ck * CHW;
  float* qkv = big;
  float* att = big + 3 * NQ;
  float* fo  = big + 4 * NQ;
  float* bo  = big + 5 * NQ;

  // --- face patch embed (chunked over batch) ---
  for (int c0 = 0; c0 < BATCH; c0 += ck) {
    const float* xin = face + (size_t)c0 * 3 * H1 * H1;
    conv7_mfma<<<dim3(7, 14, ck), 256, 0, stream>>>(xin, f_w1, f_bn, sb0);
    conv3_mfma<<<dim3(7, 28, ck), 256, 0, stream>>>(sb0, f_w23, f_bn + 128, sb1);
    conv3_mfma<<<dim3(7, 28, ck), 256, 0, stream>>>(sb1, f_w23 + 36864, f_bn + 256, sb0);
    proj8_mfma<<<dim3(13, 3, ck), 256, 0, stream>>>(sb0, f_pw, f_pb, embf + (size_t)c0 * C2 * P2);
  }

  // --- body patch embed (chunked over batch) ---
  for (int c0 = 0; c0 < BATCH; c0 += ck) {
    const float* xin = body + (size_t)c0 * 3 * H1 * H1;
    conv7_mfma<<<dim3(7, 14, ck), 256, 0, stream>>>(xin, b_w1, b_bn, sb0);
    conv3_mfma<<<dim3(7, 28, ck), 256, 0, stream>>>(sb0, b_w23, b_bn + 128, sb1);
    conv3_mfma<<<dim3(7, 28, ck), 256, 0, stream>>>(sb1, b_w23 + 36864, b_bn + 256, sb0);
    proj8_mfma<<<dim3(13, 3, ck), 256, 0, stream>>>(sb0, b_pw, b_pb, embb + (size_t)c0 * C2 * P2);
  }

  // --- attention 1: q from face-embed, k/v from body-embed ---
  qkv192<<<dim3(4, 144, BATCH), 256, 0, stream>>>(embf, embb, a1_qkv_w, a1_qkv_b, qkv);
  attn_core<<<dim3(C2, BATCH), 256, 0, stream>>>(qkv, att);
  pw192<<<dim3(4, 48, BATCH), 256, 0, stream>>>(att, a1_o_w, a1_o_b, fo);

  // --- attention 2: q from body-embed, k/v from face-embed ---
  qkv192<<<dim3(4, 144, BATCH), 256, 0, stream>>>(embb, embf, a2_qkv_w, a2_qkv_b, qkv);
  attn_core<<<dim3(C2, BATCH), 256, 0, stream>>>(qkv, att);
  pw192<<<dim3(4, 48, BATCH), 256, 0, stream>>>(att, a2_o_w, a2_o_b, bo);

  // --- concat + cov 1x1 + BN + ReLU ---
  cov_bnrelu<<<dim3(4, 48, BATCH), 256, 0, stream>>>(fo, bo, cov_w, cov_g, cov_b, out);
}

// Round 12
// 1465.303 us; speedup vs baseline: 10.7920x; 2.3238x over previous
//
#include <hip/hip_runtime.h>
#include <hip/hip_bf16.h>
#include <math.h>

#define BATCH 16
#define H1 224
#define C1 64
#define HP 28
#define P2 784            // 28*28
#define C2 192
#define NQ ((size_t)BATCH*C2*P2)       // 2408448
#define CHW ((size_t)C1*H1*H1)         // 3211264 elems per image
#define W3SZ 23040                      // one conv3 weight chunk in bf16 LDS layout
#define WPSZ 786432                     // one stream's proj weights (192*4096)

typedef __attribute__((ext_vector_type(8))) short short8;
typedef __attribute__((ext_vector_type(4))) short s16x4;
typedef __attribute__((ext_vector_type(4))) float f32x4;

__device__ __forceinline__ ushort f2bf(float v) {
  __hip_bfloat16 h = __float2bfloat16(v);
  return *(ushort*)&h;
}

// ---- one-time weight prep: conv3 weights -> bf16 [s][l][chunk][och][tap][40] ----
__global__ __launch_bounds__(256) void wprep3(
    const float* __restrict__ fw, const float* __restrict__ bw,
    ushort* __restrict__ dst)
{
  int e = blockIdx.x * 256 + threadIdx.x;
  if (e >= 184320) return;
  int i = e % 40;
  int r = e / 40;
  int t = r % 9; r /= 9;
  int o = r % 64; r /= 64;
  int c = r % 2; r /= 2;
  int l = r % 2; int s = r / 2;
  float v = 0.f;
  if (i < 32) {
    const float* wsrc = s ? bw : fw;
    v = wsrc[l * 36864 + o * 576 + (c * 32 + i) * 9 + t];
  }
  dst[e] = f2bf(v);
}

// ---- one-time cast of proj weights f32 -> bf16 (layout preserved [o][4096]) ----
__global__ __launch_bounds__(256) void cast_bf16(
    const float* __restrict__ src, ushort* __restrict__ dst, int n)
{
  int i = blockIdx.x * 256 + threadIdx.x;
  if (i < n) dst[i] = f2bf(src[i]);
}

// ---------------- conv 7x7 pad3 (3->64) + BN + ReLU, bf16 MFMA ----------------
// grid (7, 14, ck), block 256 (4 waves). OUTPUT bf16.
__global__ __launch_bounds__(256) void conv7_mfma(
    const float* __restrict__ x, const float* __restrict__ w,
    const float* __restrict__ bn, ushort* __restrict__ out)
{
  __shared__ ushort in_lds[22 * 160];   //  7040 B
  __shared__ ushort w_lds[64 * 232];    // 29696 B
  int tid = threadIdx.x;
  int wv = tid >> 6, lane = tid & 63;
  int l15 = lane & 15, q = lane >> 4;
  int x0 = blockIdx.x * 32, y0 = blockIdx.y * 16;
  int b = blockIdx.z;

  for (int k = tid; k < 3520; k += 256) {
    int i = k & 3;
    int t = k >> 2;
    int col = t % 40, row = t / 40;
    int gy = y0 - 3 + row, gx = x0 - 3 + col;
    float v = 0.0f;
    if (i < 3 && col < 38 && gy >= 0 && gy < H1 && gx >= 0 && gx < H1)
      v = x[((size_t)(b * 3 + i) * H1 + gy) * H1 + gx];
    in_lds[row * 160 + col * 4 + i] = f2bf(v);
  }
  for (int k = tid; k < 14336; k += 256) {
    int och = k / 224;
    int rem = k - och * 224;
    int dy = rem >> 5, kk = rem & 31;
    int dx = kk >> 2, i = kk & 3;
    float v = 0.0f;
    if (i < 3 && dx < 7) v = w[och * 147 + i * 49 + dy * 7 + dx];
    w_lds[och * 232 + dy * 32 + kk] = f2bf(v);
  }
  __syncthreads();

  f32x4 acc[4][8];
  #pragma unroll
  for (int m = 0; m < 4; m++)
    #pragma unroll
    for (int n = 0; n < 8; n++) acc[m][n] = (f32x4){0.f, 0.f, 0.f, 0.f};

  #pragma unroll
  for (int dy = 0; dy < 7; dy++) {
    short8 afr[4];
    #pragma unroll
    for (int m = 0; m < 4; m++)
      afr[m] = *(const short8*)&w_lds[(m * 16 + l15) * 232 + dy * 32 + q * 8];
    #pragma unroll
    for (int n = 0; n < 8; n++) {
      int r = 4 * wv + (n >> 1) + dy;
      int c = (n & 1) * 16 + l15;
      int e = r * 160 + c * 4 + q * 8;
      s16x4 lo = *(const s16x4*)&in_lds[e];
      s16x4 hi = *(const s16x4*)&in_lds[e + 4];
      short8 bfr = __builtin_shufflevector(lo, hi, 0, 1, 2, 3, 4, 5, 6, 7);
      #pragma unroll
      for (int m = 0; m < 4; m++)
        acc[m][n] = __builtin_amdgcn_mfma_f32_16x16x32_bf16(
            afr[m], bfr, acc[m][n], 0, 0, 0);
    }
  }

  const float inv = 1.0f / sqrtf(1.0f + 1e-5f);
  #pragma unroll
  for (int m = 0; m < 4; m++) {
    #pragma unroll
    for (int n = 0; n < 8; n++) {
      int py = y0 + 4 * wv + (n >> 1);
      int px = x0 + (n & 1) * 16 + l15;
      #pragma unroll
      for (int j = 0; j < 4; j++) {
        int och = m * 16 + q * 4 + j;
        float sc = bn[och] * inv, be = bn[64 + och];
        float v = fmaxf(acc[m][n][j] * sc + be, 0.0f);
        out[((size_t)(b * C1 + och) * H1 + py) * H1 + px] = f2bf(v);
      }
    }
  }
}

// ---------------- conv 3x3 pad1 (64->64) + BN + ReLU, bf16 MFMA ----------------
// grid (7, 28, ck), block 256 (4 waves). bf16 in/out; weights preconverted.
__global__ __launch_bounds__(256) void conv3_mfma(
    const ushort* __restrict__ x, const ushort* __restrict__ wp,
    const float* __restrict__ bn, ushort* __restrict__ out)
{
  __shared__ ushort in_lds[10][34][40];  // [row][col][ich] (ich 32..39 pad, unused)
  __shared__ ushort w_lds[W3SZ];         // [och][tap][40]
  int tid = threadIdx.x;
  int wv = tid >> 6, lane = tid & 63;
  int l15 = lane & 15, q = lane >> 4;
  int x0 = blockIdx.x * 32, y0 = blockIdx.y * 8;
  int b = blockIdx.z;

  f32x4 acc[4][4];
  #pragma unroll
  for (int m = 0; m < 4; m++)
    #pragma unroll
    for (int n = 0; n < 4; n++) acc[m][n] = (f32x4){0.f, 0.f, 0.f, 0.f};

  for (int ic = 0; ic < 2; ic++) {
    int ich0 = ic * 32;
    __syncthreads();
    // input: 1360 octets (o8 slow, c fast -> coalesced 2B x 64 lanes per plane)
    for (int oct = tid; oct < 1360; oct += 256) {
      int o8 = oct / 340;
      int t = oct - o8 * 340;
      int c = t % 34, r = t / 34;
      int gy = y0 - 1 + r, gx = x0 - 1 + c;
      short8 v = (short8){0, 0, 0, 0, 0, 0, 0, 0};
      if (gy >= 0 && gy < H1 && gx >= 0 && gx < H1) {
        const ushort* sp = x + ((size_t)(b * C1 + ich0 + o8 * 8) * H1 + gy) * H1 + gx;
        #pragma unroll
        for (int j = 0; j < 8; j++) v[j] = (short)sp[(size_t)j * H1 * H1];
      }
      *(short8*)&in_lds[r][c][o8 * 8] = v;
    }
    // weights: pure b128 copies from preconverted layout
    {
      const ushort* wsrc = wp + ic * W3SZ;
      for (int f = tid; f < 2880; f += 256)
        *(short8*)&w_lds[f * 8] = *(const short8*)&wsrc[f * 8];
    }
    __syncthreads();
    #pragma unroll
    for (int dy = 0; dy < 3; dy++) {
      #pragma unroll
      for (int dx = 0; dx < 3; dx++) {
        int tap = dy * 3 + dx;
        short8 afr[4];
        #pragma unroll
        for (int m = 0; m < 4; m++)
          afr[m] = *(const short8*)&w_lds[(m * 16 + l15) * 360 + tap * 40 + q * 8];
        short8 bfr[4];
        #pragma unroll
        for (int n = 0; n < 4; n++) {
          int r = 2 * wv + (n >> 1) + dy;
          int c = (n & 1) * 16 + l15 + dx;
          bfr[n] = *(const short8*)&in_lds[r][c][q * 8];
        }
        #pragma unroll
        for (int m = 0; m < 4; m++)
          #pragma unroll
          for (int n = 0; n < 4; n++)
            acc[m][n] = __builtin_amdgcn_mfma_f32_16x16x32_bf16(
                afr[m], bfr[n], acc[m][n], 0, 0, 0);
      }
    }
  }
  const float inv = 1.0f / sqrtf(1.0f + 1e-5f);
  #pragma unroll
  for (int m = 0; m < 4; m++) {
    #pragma unroll
    for (int n = 0; n < 4; n++) {
      int py = y0 + 2 * wv + (n >> 1);
      int px = x0 + (n & 1) * 16 + l15;
      #pragma unroll
      for (int j = 0; j < 4; j++) {
        int och = m * 16 + q * 4 + j;
        float sc = bn[och] * inv, be = bn[64 + och];
        float v = fmaxf(acc[m][n][j] * sc + be, 0.0f);
        out[((size_t)(b * C1 + och) * H1 + py) * H1 + px] = f2bf(v);
      }
    }
  }
}

// ---------------- proj conv 8x8 stride 8 (64->192) + bias, bf16 MFMA ----------
// grid (13, 3, ck), block 256 (4 waves 2x2). bf16 input + preconverted weights.
__global__ __launch_bounds__(256) void proj8_mfma(
    const ushort* __restrict__ x, const ushort* __restrict__ wp,
    const float* __restrict__ bias, float* __restrict__ out)
{
  __shared__ ushort a_lds[64 * 136];  // weights [o][k]
  __shared__ ushort b_lds[64 * 136];  // patches [p][k]
  int tid = threadIdx.x;
  int wv = tid >> 6, lane = tid & 63;
  int l15 = lane & 15, q = lane >> 4;
  int wm = wv >> 1, wn = wv & 1;
  int p0 = blockIdx.x * 64, o0 = blockIdx.y * 64;
  int b = blockIdx.z;

  f32x4 acc[2][2];
  #pragma unroll
  for (int m = 0; m < 2; m++)
    #pragma unroll
    for (int n = 0; n < 2; n++) acc[m][n] = (f32x4){0.f, 0.f, 0.f, 0.f};

  for (int ic0 = 0; ic0 < 64; ic0 += 2) {
    __syncthreads();
    // weights: b128 copies (r8 fast -> coalesced)
    for (int f = tid; f < 1024; f += 256) {
      int oo = f >> 4, r8 = f & 15;
      *(short8*)&a_lds[oo * 136 + r8 * 8] =
          *(const short8*)&wp[(size_t)(o0 + oo) * 4096 + ic0 * 64 + r8 * 8];
    }
    // patches: b128 loads (pp fast -> 16B x 64 lanes coalesced)
    for (int f = tid; f < 1024; f += 256) {
      int pp = f & 63, rr = f >> 6;
      int ic = rr >> 3, dy = rr & 7;
      int p = p0 + pp;
      short8 v = (short8){0, 0, 0, 0, 0, 0, 0, 0};
      if (p < P2) {
        int py = p / 28, px = p - 28 * py;
        v = *(const short8*)&x[((size_t)(b * C1 + ic0 + ic) * H1 + 8 * py + dy) * H1 + 8 * px];
      }
      *(short8*)&b_lds[pp * 136 + ic * 64 + dy * 8] = v;
    }
    __syncthreads();
    #pragma unroll
    for (int ks = 0; ks < 4; ks++) {
      short8 afr[2], bfr[2];
      #pragma unroll
      for (int m = 0; m < 2; m++)
        afr[m] = *(const short8*)&a_lds[(wm * 32 + m * 16 + l15) * 136 + ks * 32 + q * 8];
      #pragma unroll
      for (int n = 0; n < 2; n++)
        bfr[n] = *(const short8*)&b_lds[(wn * 32 + n * 16 + l15) * 136 + ks * 32 + q * 8];
      #pragma unroll
      for (int m = 0; m < 2; m++)
        #pragma unroll
        for (int n = 0; n < 2; n++)
          acc[m][n] = __builtin_amdgcn_mfma_f32_16x16x32_bf16(
              afr[m], bfr[n], acc[m][n], 0, 0, 0);
    }
  }
  #pragma unroll
  for (int m = 0; m < 2; m++) {
    #pragma unroll
    for (int n = 0; n < 2; n++) {
      int p = p0 + wn * 32 + n * 16 + l15;
      if (p >= P2) continue;
      #pragma unroll
      for (int j = 0; j < 4; j++) {
        int o = o0 + wm * 32 + m * 16 + q * 4 + j;
        out[((size_t)(b * C2 + o)) * P2 + p] = acc[m][n][j] + bias[o];
      }
    }
  }
}

// ---------------- fused q/k/v 1x1 projections ----------------
__global__ __launch_bounds__(256) void qkv192(
    const float* __restrict__ xq, const float* __restrict__ xkv,
    const float* __restrict__ w, const float* __restrict__ bias,
    float* __restrict__ out)
{
  int p = blockIdx.x * 256 + threadIdx.x;
  if (p >= P2) return;
  int by = blockIdx.y;
  int which = by / 48, o0 = (by % 48) * 4;
  int b = blockIdx.z;
  const float* xp = (which == 0 ? xq : xkv) + (size_t)b * C2 * P2 + p;
  const float* wp = w + (size_t)which * C2 * C2 + (size_t)o0 * C2;
  float a0 = bias[which * C2 + o0 + 0];
  float a1 = bias[which * C2 + o0 + 1];
  float a2 = bias[which * C2 + o0 + 2];
  float a3 = bias[which * C2 + o0 + 3];
  #pragma unroll 8
  for (int c = 0; c < C2; c++) {
    float xv = xp[(size_t)c * P2];
    a0 = fmaf(wp[c], xv, a0);
    a1 = fmaf(wp[C2 + c], xv, a1);
    a2 = fmaf(wp[2 * C2 + c], xv, a2);
    a3 = fmaf(wp[3 * C2 + c], xv, a3);
  }
  float* op = out + (size_t)which * NQ + ((size_t)b * C2 + o0) * P2 + p;
  op[0] = a0; op[P2] = a1; op[2 * P2] = a2; op[3 * P2] = a3;
}

// ---------------- per-(b,c) attention core ----------------
__global__ __launch_bounds__(256) void attn_core(
    const float* __restrict__ qkv, float* __restrict__ out)
{
  __shared__ __align__(16) float qs[P2], ks[P2], vs[P2];
  __shared__ __align__(16) float As[28][29];
  int c = blockIdx.x, b = blockIdx.y;
  int tid = threadIdx.x;
  size_t base = ((size_t)b * C2 + c) * P2;
  const float* Q = qkv + base;
  const float* K = qkv + NQ + base;
  const float* V = qkv + 2 * NQ + base;
  for (int idx = tid; idx < P2; idx += 256) {
    qs[idx] = Q[idx]; ks[idx] = K[idx]; vs[idx] = V[idx];
  }
  __syncthreads();
  const float scl = 1.0f / sqrtf(28.0f);
  for (int idx = tid; idx < P2; idx += 256) {
    int h = idx / 28, g = idx - 28 * h;
    float s = 0.f;
    #pragma unroll
    for (int ww = 0; ww < 28; ww++) s = fmaf(qs[h * 28 + ww], ks[g * 28 + ww], s);
    As[h][g] = s * scl;
  }
  __syncthreads();
  if (tid < 28) {
    float m = -1e30f;
    #pragma unroll
    for (int g = 0; g < 28; g++) m = fmaxf(m, As[tid][g]);
    float sum = 0.f;
    #pragma unroll
    for (int g = 0; g < 28; g++) {
      float e = expf(As[tid][g] - m);
      As[tid][g] = e;
      sum += e;
    }
    float r = 1.0f / sum;
    #pragma unroll
    for (int g = 0; g < 28; g++) As[tid][g] *= r;
  }
  __syncthreads();
  for (int idx = tid; idx < P2; idx += 256) {
    int h = idx / 28, ww = idx - 28 * h;
    float s = 0.f;
    #pragma unroll
    for (int g = 0; g < 28; g++) s = fmaf(As[h][g], vs[g * 28 + ww], s);
    out[base + idx] = s;
  }
}

// ---------------- 1x1 conv 192->192 + bias (attention o-proj) ----------------
__global__ __launch_bounds__(256) void pw192(
    const float* __restrict__ x, const float* __restrict__ w,
    const float* __restrict__ bias, float* __restrict__ out)
{
  int p = blockIdx.x * 256 + threadIdx.x;
  if (p >= P2) return;
  int o0 = blockIdx.y * 4;
  int b = blockIdx.z;
  const float* xp = x + (size_t)b * C2 * P2 + p;
  const float* wp = w + (size_t)o0 * C2;
  float a0 = bias[o0 + 0], a1 = bias[o0 + 1], a2 = bias[o0 + 2], a3 = bias[o0 + 3];
  #pragma unroll 8
  for (int c = 0; c < C2; c++) {
    float xv = xp[(size_t)c * P2];
    a0 = fmaf(wp[c], xv, a0);
    a1 = fmaf(wp[C2 + c], xv, a1);
    a2 = fmaf(wp[2 * C2 + c], xv, a2);
    a3 = fmaf(wp[3 * C2 + c], xv, a3);
  }
  float* op = out + ((size_t)b * C2 + o0) * P2 + p;
  op[0] = a0; op[P2] = a1; op[2 * P2] = a2; op[3 * P2] = a3;
}

// ---------------- concat + 1x1 conv 384->192 + BN + ReLU ----------------
__global__ __launch_bounds__(256) void cov_bnrelu(
    const float* __restrict__ fo, const float* __restrict__ bo,
    const float* __restrict__ w, const float* __restrict__ g,
    const float* __restrict__ be, float* __restrict__ out)
{
  int p = blockIdx.x * 256 + threadIdx.x;
  if (p >= P2) return;
  int o0 = blockIdx.y * 4;
  int b = blockIdx.z;
  float a[4] = {0.f, 0.f, 0.f, 0.f};
  const float* wp = w + (size_t)o0 * 384;
  const float* xp = fo + (size_t)b * C2 * P2 + p;
  #pragma unroll 8
  for (int c = 0; c < C2; c++) {
    float xv = xp[(size_t)c * P2];
    #pragma unroll
    for (int oo = 0; oo < 4; oo++) a[oo] = fmaf(wp[oo * 384 + c], xv, a[oo]);
  }
  xp = bo + (size_t)b * C2 * P2 + p;
  #pragma unroll 8
  for (int c = 0; c < C2; c++) {
    float xv = xp[(size_t)c * P2];
    #pragma unroll
    for (int oo = 0; oo < 4; oo++) a[oo] = fmaf(wp[oo * 384 + 192 + c], xv, a[oo]);
  }
  const float inv = 1.0f / sqrtf(1.0f + 1e-5f);
  #pragma unroll
  for (int oo = 0; oo < 4; oo++) {
    int o = o0 + oo;
    out[((size_t)b * C2 + o) * P2 + p] = fmaxf(a[oo] * (g[o] * inv) + be[o], 0.0f);
  }
}

extern "C" void kernel_launch(void* const* d_in, const int* in_sizes, int n_in,
                              void* d_out, int out_size, void* d_ws, size_t ws_size,
                              hipStream_t stream) {
  (void)in_sizes; (void)n_in; (void)out_size;
  const float* face = (const float*)d_in[0];
  const float* body = (const float*)d_in[1];
  const float* f_w1 = (const float*)d_in[2];
  const float* f_w23 = (const float*)d_in[3];
  const float* f_bn = (const float*)d_in[4];
  const float* f_pw = (const float*)d_in[5];
  const float* f_pb = (const float*)d_in[6];
  const float* b_w1 = (const float*)d_in[7];
  const float* b_w23 = (const float*)d_in[8];
  const float* b_bn = (const float*)d_in[9];
  const float* b_pw = (const float*)d_in[10];
  const float* b_pb = (const float*)d_in[11];
  const float* a1_qkv_w = (const float*)d_in[12];
  const float* a1_qkv_b = (const float*)d_in[13];
  const float* a1_o_w = (const float*)d_in[14];
  const float* a1_o_b = (const float*)d_in[15];
  const float* a2_qkv_w = (const float*)d_in[16];
  const float* a2_qkv_b = (const float*)d_in[17];
  const float* a2_o_w = (const float*)d_in[18];
  const float* a2_o_b = (const float*)d_in[19];
  const float* cov_w = (const float*)d_in[20];
  const float* cov_g = (const float*)d_in[21];
  const float* cov_b = (const float*)d_in[22];
  float* out = (float*)d_out;

  // ---- workspace layout ----
  // [embf NQ][embb NQ][wpre3 92160f][wpreP 786432f][big]
  // big holds bf16 sb0/sb1 (ck*CHW ushorts each = ck*CHW floats total),
  // aliased by f32 attention scratch (6*NQ) after the stems.
  size_t availF = ws_size / sizeof(float);
  const size_t preF = 92160 + 786432;
  int ck = 2;
  for (int cand = 16; cand >= 4; cand >>= 1) {
    size_t bigF = (size_t)cand * CHW;
    if (bigF < 6 * NQ) bigF = 6 * NQ;
    if (2 * NQ + preF + bigF <= availF) { ck = cand; break; }
  }

  float* ws = (float*)d_ws;
  float* embf = ws;
  float* embb = ws + NQ;
  ushort* wpre3 = (ushort*)(ws + 2 * NQ);
  ushort* wpreP = (ushort*)(ws + 2 * NQ + 92160);
  float* big = ws + 2 * NQ + preF;
  ushort* sb0 = (ushort*)big;
  ushort* sb1 = (ushort*)big + (size_t)ck * CHW;
  float* qkv = big;
  float* att = big + 3 * NQ;
  float* fo  = big + 4 * NQ;
  float* bo  = big + 5 * NQ;

  // --- one-time weight prep (runs every call: graph-safe) ---
  wprep3<<<720, 256, 0, stream>>>(f_w23, b_w23, wpre3);
  cast_bf16<<<(WPSZ + 255) / 256, 256, 0, stream>>>(f_pw, wpreP, WPSZ);
  cast_bf16<<<(WPSZ + 255) / 256, 256, 0, stream>>>(b_pw, wpreP + WPSZ, WPSZ);

  // --- face patch embed (chunked over batch) ---
  for (int c0 = 0; c0 < BATCH; c0 += ck) {
    const float* xin = face + (size_t)c0 * 3 * H1 * H1;
    conv7_mfma<<<dim3(7, 14, ck), 256, 0, stream>>>(xin, f_w1, f_bn, sb0);
    conv3_mfma<<<dim3(7, 28, ck), 256, 0, stream>>>(sb0, wpre3, f_bn + 128, sb1);
    conv3_mfma<<<dim3(7, 28, ck), 256, 0, stream>>>(sb1, wpre3 + 2 * W3SZ, f_bn + 256, sb0);
    proj8_mfma<<<dim3(13, 3, ck), 256, 0, stream>>>(sb0, wpreP, f_pb, embf + (size_t)c0 * C2 * P2);
  }

  // --- body patch embed (chunked over batch) ---
  for (int c0 = 0; c0 < BATCH; c0 += ck) {
    const float* xin = body + (size_t)c0 * 3 * H1 * H1;
    conv7_mfma<<<dim3(7, 14, ck), 256, 0, stream>>>(xin, b_w1, b_bn, sb0);
    conv3_mfma<<<dim3(7, 28, ck), 256, 0, stream>>>(sb0, wpre3 + 4 * W3SZ, b_bn + 128, sb1);
    conv3_mfma<<<dim3(7, 28, ck), 256, 0, stream>>>(sb1, wpre3 + 6 * W3SZ, b_bn + 256, sb0);
    proj8_mfma<<<dim3(13, 3, ck), 256, 0, stream>>>(sb0, wpreP + WPSZ, b_pb, embb + (size_t)c0 * C2 * P2);
  }

  // --- attention 1: q from face-embed, k/v from body-embed ---
  qkv192<<<dim3(4, 144, BATCH), 256, 0, stream>>>(embf, embb, a1_qkv_w, a1_qkv_b, qkv);
  attn_core<<<dim3(C2, BATCH), 256, 0, stream>>>(qkv, att);
  pw192<<<dim3(4, 48, BATCH), 256, 0, stream>>>(att, a1_o_w, a1_o_b, fo);

  // --- attention 2: q from body-embed, k/v from face-embed ---
  qkv192<<<dim3(4, 144, BATCH), 256, 0, stream>>>(embb, embf, a2_qkv_w, a2_qkv_b, qkv);
  attn_core<<<dim3(C2, BATCH), 256, 0, stream>>>(qkv, att);
  pw192<<<dim3(4, 48, BATCH), 256, 0, stream>>>(att, a2_o_w, a2_o_b, bo);

  // --- concat + cov 1x1 + BN + ReLU ---
  cov_bnrelu<<<dim3(4, 48, BATCH), 256, 0, stream>>>(fo, bo, cov_w, cov_g, cov_b, out);
}

// Round 13
// 1220.164 us; speedup vs baseline: 12.9602x; 1.2009x over previous
//
#include <hip/hip_runtime.h>
#include <hip/hip_bf16.h>
#include <math.h>

#define BATCH 16
#define H1 224
#define C1 64
#define HP 28
#define P2 784            // 28*28
#define C2 192
#define NQ ((size_t)BATCH*C2*P2)       // 2408448
#define CHW ((size_t)C1*H1*H1)         // 3211264 elems per image
#define W3SZ 23040                      // one conv3 weight chunk in bf16 LDS layout
#define WPSZ 786432                     // one stream's proj weights (192*4096)

typedef __attribute__((ext_vector_type(8))) short short8;
typedef __attribute__((ext_vector_type(4))) short s16x4;
typedef __attribute__((ext_vector_type(4))) float f32x4;

__device__ __forceinline__ ushort f2bf(float v) {
  __hip_bfloat16 h = __float2bfloat16(v);
  return *(ushort*)&h;
}

// ---- one-time weight prep: conv3 weights -> bf16 [s][l][chunk][och][tap][40] ----
__global__ __launch_bounds__(256) void wprep3(
    const float* __restrict__ fw, const float* __restrict__ bw,
    ushort* __restrict__ dst)
{
  int e = blockIdx.x * 256 + threadIdx.x;
  if (e >= 184320) return;
  int i = e % 40;
  int r = e / 40;
  int t = r % 9; r /= 9;
  int o = r % 64; r /= 64;
  int c = r % 2; r /= 2;
  int l = r % 2; int s = r / 2;
  float v = 0.f;
  if (i < 32) {
    const float* wsrc = s ? bw : fw;
    v = wsrc[l * 36864 + o * 576 + (c * 32 + i) * 9 + t];
  }
  dst[e] = f2bf(v);
}

// ---- one-time cast of proj weights f32 -> bf16 (layout preserved [o][4096]) ----
__global__ __launch_bounds__(256) void cast_bf16(
    const float* __restrict__ src, ushort* __restrict__ dst, int n)
{
  int i = blockIdx.x * 256 + threadIdx.x;
  if (i < n) dst[i] = f2bf(src[i]);
}

// ---------------- conv 7x7 pad3 (3->64) + BN + ReLU, bf16 MFMA ----------------
// grid (7, 14, ck), block 256 (4 waves). OUTPUT bf16.
__global__ __launch_bounds__(256) void conv7_mfma(
    const float* __restrict__ x, const float* __restrict__ w,
    const float* __restrict__ bn, ushort* __restrict__ out)
{
  __shared__ ushort in_lds[22 * 160];   //  7040 B
  __shared__ ushort w_lds[64 * 232];    // 29696 B
  int tid = threadIdx.x;
  int wv = tid >> 6, lane = tid & 63;
  int l15 = lane & 15, q = lane >> 4;
  int x0 = blockIdx.x * 32, y0 = blockIdx.y * 16;
  int b = blockIdx.z;

  for (int k = tid; k < 3520; k += 256) {
    int i = k & 3;
    int t = k >> 2;
    int col = t % 40, row = t / 40;
    int gy = y0 - 3 + row, gx = x0 - 3 + col;
    float v = 0.0f;
    if (i < 3 && col < 38 && gy >= 0 && gy < H1 && gx >= 0 && gx < H1)
      v = x[((size_t)(b * 3 + i) * H1 + gy) * H1 + gx];
    in_lds[row * 160 + col * 4 + i] = f2bf(v);
  }
  for (int k = tid; k < 14336; k += 256) {
    int och = k / 224;
    int rem = k - och * 224;
    int dy = rem >> 5, kk = rem & 31;
    int dx = kk >> 2, i = kk & 3;
    float v = 0.0f;
    if (i < 3 && dx < 7) v = w[och * 147 + i * 49 + dy * 7 + dx];
    w_lds[och * 232 + dy * 32 + kk] = f2bf(v);
  }
  __syncthreads();

  f32x4 acc[4][8];
  #pragma unroll
  for (int m = 0; m < 4; m++)
    #pragma unroll
    for (int n = 0; n < 8; n++) acc[m][n] = (f32x4){0.f, 0.f, 0.f, 0.f};

  #pragma unroll
  for (int dy = 0; dy < 7; dy++) {
    short8 afr[4];
    #pragma unroll
    for (int m = 0; m < 4; m++)
      afr[m] = *(const short8*)&w_lds[(m * 16 + l15) * 232 + dy * 32 + q * 8];
    #pragma unroll
    for (int n = 0; n < 8; n++) {
      int r = 4 * wv + (n >> 1) + dy;
      int c = (n & 1) * 16 + l15;
      int e = r * 160 + c * 4 + q * 8;
      s16x4 lo = *(const s16x4*)&in_lds[e];
      s16x4 hi = *(const s16x4*)&in_lds[e + 4];
      short8 bfr = __builtin_shufflevector(lo, hi, 0, 1, 2, 3, 4, 5, 6, 7);
      #pragma unroll
      for (int m = 0; m < 4; m++)
        acc[m][n] = __builtin_amdgcn_mfma_f32_16x16x32_bf16(
            afr[m], bfr, acc[m][n], 0, 0, 0);
    }
  }

  const float inv = 1.0f / sqrtf(1.0f + 1e-5f);
  #pragma unroll
  for (int m = 0; m < 4; m++) {
    #pragma unroll
    for (int n = 0; n < 8; n++) {
      int py = y0 + 4 * wv + (n >> 1);
      int px = x0 + (n & 1) * 16 + l15;
      #pragma unroll
      for (int j = 0; j < 4; j++) {
        int och = m * 16 + q * 4 + j;
        float sc = bn[och] * inv, be = bn[64 + och];
        float v = fmaxf(acc[m][n][j] * sc + be, 0.0f);
        out[((size_t)(b * C1 + och) * H1 + py) * H1 + px] = f2bf(v);
      }
    }
  }
}

// ---------------- conv 3x3 pad1 (64->64) + BN + ReLU, bf16 MFMA ----------------
// grid (7, 28, ck), block 256 (4 waves). bf16 in/out; weights preconverted.
// XCD-aware bijective swizzle (T1): nwg = 196*ck, divisible by 8 for even ck.
__global__ __launch_bounds__(256) void conv3_mfma(
    const ushort* __restrict__ x, const ushort* __restrict__ wp,
    const float* __restrict__ bn, ushort* __restrict__ out)
{
  __shared__ ushort in_lds[10][34][40];  // [row][col][ich] (ich 32..39 pad)
  __shared__ ushort w_lds[W3SZ];         // [och][tap][40]
  int tid = threadIdx.x;
  int wv = tid >> 6, lane = tid & 63;
  int l15 = lane & 15, q = lane >> 4;

  // XCD swizzle: contiguous work ranges per XCD for halo/weight L2 reuse
  int flat = blockIdx.x + 7 * (blockIdx.y + 28 * blockIdx.z);
  int nwg = 196 * gridDim.z;
  int swz = (flat & 7) * (nwg >> 3) + (flat >> 3);
  int x0 = (swz % 7) * 32;
  int t0 = swz / 7;
  int y0 = (t0 % 28) * 8;
  int b = t0 / 28;

  f32x4 acc[4][4];
  #pragma unroll
  for (int m = 0; m < 4; m++)
    #pragma unroll
    for (int n = 0; n < 4; n++) acc[m][n] = (f32x4){0.f, 0.f, 0.f, 0.f};

  for (int ic = 0; ic < 2; ic++) {
    int ich0 = ic * 32;
    __syncthreads();
    for (int oct = tid; oct < 1360; oct += 256) {
      int o8 = oct / 340;
      int t = oct - o8 * 340;
      int c = t % 34, r = t / 34;
      int gy = y0 - 1 + r, gx = x0 - 1 + c;
      short8 v = (short8){0, 0, 0, 0, 0, 0, 0, 0};
      if (gy >= 0 && gy < H1 && gx >= 0 && gx < H1) {
        const ushort* sp = x + ((size_t)(b * C1 + ich0 + o8 * 8) * H1 + gy) * H1 + gx;
        #pragma unroll
        for (int j = 0; j < 8; j++) v[j] = (short)sp[(size_t)j * H1 * H1];
      }
      *(short8*)&in_lds[r][c][o8 * 8] = v;
    }
    {
      const ushort* wsrc = wp + ic * W3SZ;
      for (int f = tid; f < 2880; f += 256)
        *(short8*)&w_lds[f * 8] = *(const short8*)&wsrc[f * 8];
    }
    __syncthreads();
    #pragma unroll
    for (int dy = 0; dy < 3; dy++) {
      #pragma unroll
      for (int dx = 0; dx < 3; dx++) {
        int tap = dy * 3 + dx;
        short8 afr[4];
        #pragma unroll
        for (int m = 0; m < 4; m++)
          afr[m] = *(const short8*)&w_lds[(m * 16 + l15) * 360 + tap * 40 + q * 8];
        short8 bfr[4];
        #pragma unroll
        for (int n = 0; n < 4; n++) {
          int r = 2 * wv + (n >> 1) + dy;
          int c = (n & 1) * 16 + l15 + dx;
          bfr[n] = *(const short8*)&in_lds[r][c][q * 8];
        }
        #pragma unroll
        for (int m = 0; m < 4; m++)
          #pragma unroll
          for (int n = 0; n < 4; n++)
            acc[m][n] = __builtin_amdgcn_mfma_f32_16x16x32_bf16(
                afr[m], bfr[n], acc[m][n], 0, 0, 0);
      }
    }
  }
  const float inv = 1.0f / sqrtf(1.0f + 1e-5f);
  #pragma unroll
  for (int m = 0; m < 4; m++) {
    #pragma unroll
    for (int n = 0; n < 4; n++) {
      int py = y0 + 2 * wv + (n >> 1);
      int px = x0 + (n & 1) * 16 + l15;
      #pragma unroll
      for (int j = 0; j < 4; j++) {
        int och = m * 16 + q * 4 + j;
        float sc = bn[och] * inv, be = bn[64 + och];
        float v = fmaxf(acc[m][n][j] * sc + be, 0.0f);
        out[((size_t)(b * C1 + och) * H1 + py) * H1 + px] = f2bf(v);
      }
    }
  }
}

// ---------------- proj conv 8x8 stride 8 (64->192) + bias, bf16 MFMA ----------
__global__ __launch_bounds__(256) void proj8_mfma(
    const ushort* __restrict__ x, const ushort* __restrict__ wp,
    const float* __restrict__ bias, float* __restrict__ out)
{
  __shared__ ushort a_lds[64 * 136];  // weights [o][k]
  __shared__ ushort b_lds[64 * 136];  // patches [p][k]
  int tid = threadIdx.x;
  int wv = tid >> 6, lane = tid & 63;
  int l15 = lane & 15, q = lane >> 4;
  int wm = wv >> 1, wn = wv & 1;
  int p0 = blockIdx.x * 64, o0 = blockIdx.y * 64;
  int b = blockIdx.z;

  f32x4 acc[2][2];
  #pragma unroll
  for (int m = 0; m < 2; m++)
    #pragma unroll
    for (int n = 0; n < 2; n++) acc[m][n] = (f32x4){0.f, 0.f, 0.f, 0.f};

  for (int ic0 = 0; ic0 < 64; ic0 += 2) {
    __syncthreads();
    for (int f = tid; f < 1024; f += 256) {
      int oo = f >> 4, r8 = f & 15;
      *(short8*)&a_lds[oo * 136 + r8 * 8] =
          *(const short8*)&wp[(size_t)(o0 + oo) * 4096 + ic0 * 64 + r8 * 8];
    }
    for (int f = tid; f < 1024; f += 256) {
      int pp = f & 63, rr = f >> 6;
      int ic = rr >> 3, dy = rr & 7;
      int p = p0 + pp;
      short8 v = (short8){0, 0, 0, 0, 0, 0, 0, 0};
      if (p < P2) {
        int py = p / 28, px = p - 28 * py;
        v = *(const short8*)&x[((size_t)(b * C1 + ic0 + ic) * H1 + 8 * py + dy) * H1 + 8 * px];
      }
      *(short8*)&b_lds[pp * 136 + ic * 64 + dy * 8] = v;
    }
    __syncthreads();
    #pragma unroll
    for (int ks = 0; ks < 4; ks++) {
      short8 afr[2], bfr[2];
      #pragma unroll
      for (int m = 0; m < 2; m++)
        afr[m] = *(const short8*)&a_lds[(wm * 32 + m * 16 + l15) * 136 + ks * 32 + q * 8];
      #pragma unroll
      for (int n = 0; n < 2; n++)
        bfr[n] = *(const short8*)&b_lds[(wn * 32 + n * 16 + l15) * 136 + ks * 32 + q * 8];
      #pragma unroll
      for (int m = 0; m < 2; m++)
        #pragma unroll
        for (int n = 0; n < 2; n++)
          acc[m][n] = __builtin_amdgcn_mfma_f32_16x16x32_bf16(
              afr[m], bfr[n], acc[m][n], 0, 0, 0);
    }
  }
  #pragma unroll
  for (int m = 0; m < 2; m++) {
    #pragma unroll
    for (int n = 0; n < 2; n++) {
      int p = p0 + wn * 32 + n * 16 + l15;
      if (p >= P2) continue;
      #pragma unroll
      for (int j = 0; j < 4; j++) {
        int o = o0 + wm * 32 + m * 16 + q * 4 + j;
        out[((size_t)(b * C2 + o)) * P2 + p] = acc[m][n][j] + bias[o];
      }
    }
  }
}

// ------------- 1x1 192->192 GEMM + bias, bf16 MFMA (qkv & o-proj) -------------
// grid (13, 3*NW, B): which = y/3 (0 for o-proj), o-tile = y%3.
// C[o,p] = bias[o] + sum_c w[which][o][c] * X[b][c][p]; X = which==0 ? Xq : Xkv.
// LDS stride 200 (400 B): b128 r/w = exactly 8 accesses/bank (optimal).
__global__ __launch_bounds__(256) void pw_mfma(
    const float* __restrict__ Xq, const float* __restrict__ Xkv,
    const float* __restrict__ w, const float* __restrict__ bias,
    float* __restrict__ out)
{
  __shared__ ushort a_lds[64 * 200];  // w rows [o][k]
  __shared__ ushort b_lds[64 * 200];  // x cols [p][k]
  int tid = threadIdx.x;
  int wv = tid >> 6, lane = tid & 63;
  int l15 = lane & 15, q = lane >> 4;
  int wm = wv >> 1, wn = wv & 1;
  int p0 = blockIdx.x * 64;
  int which = blockIdx.y / 3, o0 = (blockIdx.y % 3) * 64;
  int b = blockIdx.z;
  const float* X = (which == 0 ? Xq : Xkv) + (size_t)b * C2 * P2;
  const float* wp = w + (size_t)which * C2 * C2;

  // stage w: 64 o x 192 k (k8-fast within row -> coalesced-ish; L2-hot anyway)
  for (int f = tid; f < 1536; f += 256) {
    int oo = f / 24, k8 = f % 24;
    const float* src = wp + (size_t)(o0 + oo) * C2 + k8 * 8;
    ushort* dst = &a_lds[oo * 200 + k8 * 8];
    #pragma unroll
    for (int j = 0; j < 8; j++) dst[j] = f2bf(src[j]);
  }
  // stage x: pp-fast gather (coalesced 4B x 64 per c-plane), b128 LDS write
  for (int f = tid; f < 1536; f += 256) {
    int pp = f & 63, c8 = f >> 6;
    int p = p0 + pp;
    short8 v = (short8){0, 0, 0, 0, 0, 0, 0, 0};
    if (p < P2) {
      #pragma unroll
      for (int j = 0; j < 8; j++)
        v[j] = (short)f2bf(X[(size_t)(c8 * 8 + j) * P2 + p]);
    }
    *(short8*)&b_lds[pp * 200 + c8 * 8] = v;
  }
  __syncthreads();

  f32x4 acc[2][2];
  #pragma unroll
  for (int m = 0; m < 2; m++)
    #pragma unroll
    for (int n = 0; n < 2; n++) acc[m][n] = (f32x4){0.f, 0.f, 0.f, 0.f};

  #pragma unroll
  for (int ks = 0; ks < 6; ks++) {
    short8 afr[2], bfr[2];
    #pragma unroll
    for (int m = 0; m < 2; m++)
      afr[m] = *(const short8*)&a_lds[(wm * 32 + m * 16 + l15) * 200 + ks * 32 + q * 8];
    #pragma unroll
    for (int n = 0; n < 2; n++)
      bfr[n] = *(const short8*)&b_lds[(wn * 32 + n * 16 + l15) * 200 + ks * 32 + q * 8];
    #pragma unroll
    for (int m = 0; m < 2; m++)
      #pragma unroll
      for (int n = 0; n < 2; n++)
        acc[m][n] = __builtin_amdgcn_mfma_f32_16x16x32_bf16(
            afr[m], bfr[n], acc[m][n], 0, 0, 0);
  }

  float* op = out + (size_t)which * NQ + (size_t)b * C2 * P2;
  #pragma unroll
  for (int m = 0; m < 2; m++) {
    #pragma unroll
    for (int n = 0; n < 2; n++) {
      int p = p0 + wn * 32 + n * 16 + l15;
      if (p >= P2) continue;
      #pragma unroll
      for (int j = 0; j < 4; j++) {
        int o = o0 + wm * 32 + m * 16 + q * 4 + j;
        op[(size_t)o * P2 + p] = acc[m][n][j] + bias[which * C2 + o];
      }
    }
  }
}

// ------- concat + 1x1 384->192 + BN + ReLU, bf16 MFMA (2 chunks of K=192) -----
// grid (13, 3, B). w row-major [o][384]; chunk 0 reads fo, chunk 1 reads bo.
__global__ __launch_bounds__(256) void cov_mfma(
    const float* __restrict__ fo, const float* __restrict__ bo,
    const float* __restrict__ w, const float* __restrict__ g,
    const float* __restrict__ be, float* __restrict__ out)
{
  __shared__ ushort a_lds[64 * 200];
  __shared__ ushort b_lds[64 * 200];
  int tid = threadIdx.x;
  int wv = tid >> 6, lane = tid & 63;
  int l15 = lane & 15, q = lane >> 4;
  int wm = wv >> 1, wn = wv & 1;
  int p0 = blockIdx.x * 64, o0 = blockIdx.y * 64;
  int b = blockIdx.z;

  f32x4 acc[2][2];
  #pragma unroll
  for (int m = 0; m < 2; m++)
    #pragma unroll
    for (int n = 0; n < 2; n++) acc[m][n] = (f32x4){0.f, 0.f, 0.f, 0.f};

  for (int cc = 0; cc < 2; cc++) {
    const float* X = (cc ? bo : fo) + (size_t)b * C2 * P2;
    __syncthreads();
    for (int f = tid; f < 1536; f += 256) {
      int oo = f / 24, k8 = f % 24;
      const float* src = w + (size_t)(o0 + oo) * 384 + cc * C2 + k8 * 8;
      ushort* dst = &a_lds[oo * 200 + k8 * 8];
      #pragma unroll
      for (int j = 0; j < 8; j++) dst[j] = f2bf(src[j]);
    }
    for (int f = tid; f < 1536; f += 256) {
      int pp = f & 63, c8 = f >> 6;
      int p = p0 + pp;
      short8 v = (short8){0, 0, 0, 0, 0, 0, 0, 0};
      if (p < P2) {
        #pragma unroll
        for (int j = 0; j < 8; j++)
          v[j] = (short)f2bf(X[(size_t)(c8 * 8 + j) * P2 + p]);
      }
      *(short8*)&b_lds[pp * 200 + c8 * 8] = v;
    }
    __syncthreads();
    #pragma unroll
    for (int ks = 0; ks < 6; ks++) {
      short8 afr[2], bfr[2];
      #pragma unroll
      for (int m = 0; m < 2; m++)
        afr[m] = *(const short8*)&a_lds[(wm * 32 + m * 16 + l15) * 200 + ks * 32 + q * 8];
      #pragma unroll
      for (int n = 0; n < 2; n++)
        bfr[n] = *(const short8*)&b_lds[(wn * 32 + n * 16 + l15) * 200 + ks * 32 + q * 8];
      #pragma unroll
      for (int m = 0; m < 2; m++)
        #pragma unroll
        for (int n = 0; n < 2; n++)
          acc[m][n] = __builtin_amdgcn_mfma_f32_16x16x32_bf16(
              afr[m], bfr[n], acc[m][n], 0, 0, 0);
    }
  }

  const float inv = 1.0f / sqrtf(1.0f + 1e-5f);
  #pragma unroll
  for (int m = 0; m < 2; m++) {
    #pragma unroll
    for (int n = 0; n < 2; n++) {
      int p = p0 + wn * 32 + n * 16 + l15;
      if (p >= P2) continue;
      #pragma unroll
      for (int j = 0; j < 4; j++) {
        int o = o0 + wm * 32 + m * 16 + q * 4 + j;
        float v = fmaxf(acc[m][n][j] * (g[o] * inv) + be[o], 0.0f);
        out[((size_t)b * C2 + o) * P2 + p] = v;
      }
    }
  }
}

// ---------------- per-(b,c) attention core ----------------
__global__ __launch_bounds__(256) void attn_core(
    const float* __restrict__ qkv, float* __restrict__ out)
{
  __shared__ __align__(16) float qs[P2], ks[P2], vs[P2];
  __shared__ __align__(16) float As[28][29];
  int c = blockIdx.x, b = blockIdx.y;
  int tid = threadIdx.x;
  size_t base = ((size_t)b * C2 + c) * P2;
  const float* Q = qkv + base;
  const float* K = qkv + NQ + base;
  const float* V = qkv + 2 * NQ + base;
  for (int idx = tid; idx < P2; idx += 256) {
    qs[idx] = Q[idx]; ks[idx] = K[idx]; vs[idx] = V[idx];
  }
  __syncthreads();
  const float scl = 1.0f / sqrtf(28.0f);
  for (int idx = tid; idx < P2; idx += 256) {
    int h = idx / 28, g = idx - 28 * h;
    float s = 0.f;
    #pragma unroll
    for (int ww = 0; ww < 28; ww++) s = fmaf(qs[h * 28 + ww], ks[g * 28 + ww], s);
    As[h][g] = s * scl;
  }
  __syncthreads();
  if (tid < 28) {
    float m = -1e30f;
    #pragma unroll
    for (int g = 0; g < 28; g++) m = fmaxf(m, As[tid][g]);
    float sum = 0.f;
    #pragma unroll
    for (int g = 0; g < 28; g++) {
      float e = expf(As[tid][g] - m);
      As[tid][g] = e;
      sum += e;
    }
    float r = 1.0f / sum;
    #pragma unroll
    for (int g = 0; g < 28; g++) As[tid][g] *= r;
  }
  __syncthreads();
  for (int idx = tid; idx < P2; idx += 256) {
    int h = idx / 28, ww = idx - 28 * h;
    float s = 0.f;
    #pragma unroll
    for (int g = 0; g < 28; g++) s = fmaf(As[h][g], vs[g * 28 + ww], s);
    out[base + idx] = s;
  }
}

extern "C" void kernel_launch(void* const* d_in, const int* in_sizes, int n_in,
                              void* d_out, int out_size, void* d_ws, size_t ws_size,
                              hipStream_t stream) {
  (void)in_sizes; (void)n_in; (void)out_size;
  const float* face = (const float*)d_in[0];
  const float* body = (const float*)d_in[1];
  const float* f_w1 = (const float*)d_in[2];
  const float* f_w23 = (const float*)d_in[3];
  const float* f_bn = (const float*)d_in[4];
  const float* f_pw = (const float*)d_in[5];
  const float* f_pb = (const float*)d_in[6];
  const float* b_w1 = (const float*)d_in[7];
  const float* b_w23 = (const float*)d_in[8];
  const float* b_bn = (const float*)d_in[9];
  const float* b_pw = (const float*)d_in[10];
  const float* b_pb = (const float*)d_in[11];
  const float* a1_qkv_w = (const float*)d_in[12];
  const float* a1_qkv_b = (const float*)d_in[13];
  const float* a1_o_w = (const float*)d_in[14];
  const float* a1_o_b = (const float*)d_in[15];
  const float* a2_qkv_w = (const float*)d_in[16];
  const float* a2_qkv_b = (const float*)d_in[17];
  const float* a2_o_w = (const float*)d_in[18];
  const float* a2_o_b = (const float*)d_in[19];
  const float* cov_w = (const float*)d_in[20];
  const float* cov_g = (const float*)d_in[21];
  const float* cov_b = (const float*)d_in[22];
  float* out = (float*)d_out;

  // ---- workspace layout ----
  size_t availF = ws_size / sizeof(float);
  const size_t preF = 92160 + 786432;
  int ck = 2;
  for (int cand = 16; cand >= 4; cand >>= 1) {
    size_t bigF = (size_t)cand * CHW;
    if (bigF < 6 * NQ) bigF = 6 * NQ;
    if (2 * NQ + preF + bigF <= availF) { ck = cand; break; }
  }

  float* ws = (float*)d_ws;
  float* embf = ws;
  float* embb = ws + NQ;
  ushort* wpre3 = (ushort*)(ws + 2 * NQ);
  ushort* wpreP = (ushort*)(ws + 2 * NQ + 92160);
  float* big = ws + 2 * NQ + preF;
  ushort* sb0 = (ushort*)big;
  ushort* sb1 = (ushort*)big + (size_t)ck * CHW;
  float* qkv = big;
  float* att = big + 3 * NQ;
  float* fo  = big + 4 * NQ;
  float* bo  = big + 5 * NQ;

  // --- one-time weight prep (runs every call: graph-safe) ---
  wprep3<<<720, 256, 0, stream>>>(f_w23, b_w23, wpre3);
  cast_bf16<<<(WPSZ + 255) / 256, 256, 0, stream>>>(f_pw, wpreP, WPSZ);
  cast_bf16<<<(WPSZ + 255) / 256, 256, 0, stream>>>(b_pw, wpreP + WPSZ, WPSZ);

  // --- face patch embed (chunked over batch) ---
  for (int c0 = 0; c0 < BATCH; c0 += ck) {
    const float* xin = face + (size_t)c0 * 3 * H1 * H1;
    conv7_mfma<<<dim3(7, 14, ck), 256, 0, stream>>>(xin, f_w1, f_bn, sb0);
    conv3_mfma<<<dim3(7, 28, ck), 256, 0, stream>>>(sb0, wpre3, f_bn + 128, sb1);
    conv3_mfma<<<dim3(7, 28, ck), 256, 0, stream>>>(sb1, wpre3 + 2 * W3SZ, f_bn + 256, sb0);
    proj8_mfma<<<dim3(13, 3, ck), 256, 0, stream>>>(sb0, wpreP, f_pb, embf + (size_t)c0 * C2 * P2);
  }

  // --- body patch embed (chunked over batch) ---
  for (int c0 = 0; c0 < BATCH; c0 += ck) {
    const float* xin = body + (size_t)c0 * 3 * H1 * H1;
    conv7_mfma<<<dim3(7, 14, ck), 256, 0, stream>>>(xin, b_w1, b_bn, sb0);
    conv3_mfma<<<dim3(7, 28, ck), 256, 0, stream>>>(sb0, wpre3 + 4 * W3SZ, b_bn + 128, sb1);
    conv3_mfma<<<dim3(7, 28, ck), 256, 0, stream>>>(sb1, wpre3 + 6 * W3SZ, b_bn + 256, sb0);
    proj8_mfma<<<dim3(13, 3, ck), 256, 0, stream>>>(sb0, wpreP + WPSZ, b_pb, embb + (size_t)c0 * C2 * P2);
  }

  // --- attention 1: q from face-embed, k/v from body-embed ---
  pw_mfma<<<dim3(13, 9, BATCH), 256, 0, stream>>>(embf, embb, a1_qkv_w, a1_qkv_b, qkv);
  attn_core<<<dim3(C2, BATCH), 256, 0, stream>>>(qkv, att);
  pw_mfma<<<dim3(13, 3, BATCH), 256, 0, stream>>>(att, att, a1_o_w, a1_o_b, fo);

  // --- attention 2: q from body-embed, k/v from face-embed ---
  pw_mfma<<<dim3(13, 9, BATCH), 256, 0, stream>>>(embb, embf, a2_qkv_w, a2_qkv_b, qkv);
  attn_core<<<dim3(C2, BATCH), 256, 0, stream>>>(qkv, att);
  pw_mfma<<<dim3(13, 3, BATCH), 256, 0, stream>>>(att, att, a2_o_w, a2_o_b, bo);

  // --- concat + cov 1x1 + BN + ReLU ---
  cov_mfma<<<dim3(13, 3, BATCH), 256, 0, stream>>>(fo, bo, cov_w, cov_g, cov_b, out);
}